// Round 4
// baseline (424.351 us; speedup 1.0000x reference)
//
#include <hip/hip_runtime.h>
#include <hip/hip_bf16.h>
#include <cstdint>

#define AS1 __attribute__((address_space(1)))
#define AS3 __attribute__((address_space(3)))
#define SBAR() asm volatile("s_barrier" ::: "memory")

typedef __attribute__((ext_vector_type(8))) short short8x;   // 8 bf16 (4 VGPRs)
typedef __attribute__((ext_vector_type(4))) float f32x4;     // MFMA C/D

static constexpr int T    = 4096;   // tokens
static constexpr int HD   = 1024;   // hidden dim
static constexpr int FD   = 4096;   // ffn dim
static constexpr int NE   = 8;      // experts
static constexpr int P    = T * 2;  // routed pairs (top-2)
static constexpr int PPAD = P + 256;
static constexpr int MAXTILES  = P / 128 + NE;  // 72  (128-row tiles, fc2)
static constexpr int MAXT256   = P / 256 + NE;  // 40  (256-row tiles, fc1)
static constexpr int RTB  = 16;     // router tokens per block
static constexpr int RNB  = T / RTB;  // 256 router blocks

struct TileDesc { int e; int start; int rows; int pad; };

__device__ __forceinline__ uint16_t f2bf(float f) {
  uint32_t u = __builtin_bit_cast(uint32_t, f);
  u += 0x7FFFu + ((u >> 16) & 1u);
  return (uint16_t)(u >> 16);
}
__device__ __forceinline__ float bf2f(uint16_t b) {
  uint32_t u = ((uint32_t)b) << 16;
  return __builtin_bit_cast(float, u);
}

__device__ __forceinline__ void gload_lds16(const void* g, void* l) {
  __builtin_amdgcn_global_load_lds((const AS1 uint32_t*)g, (AS3 uint32_t*)l, 16, 0, 0);
}

// ---------------- x fp32 -> bf16 ----------------
__global__ __launch_bounds__(256) void cvt_x_kernel(const float* __restrict__ x,
                                                    uint16_t* __restrict__ xb) {
  size_t i = ((size_t)blockIdx.x * 256 + threadIdx.x) * 4;
  float4 v = *(const float4*)&x[i];
  ushort4 o;
  o.x = f2bf(v.x); o.y = f2bf(v.y); o.z = f2bf(v.z); o.w = f2bf(v.w);
  *(ushort4*)&xb[i] = o;
}

// ------------- transpose + cvt: in [z][R][C] f32 -> out [z][C][R] bf16 -------------
__global__ __launch_bounds__(256) void transpose_cvt_kernel(
    const float* __restrict__ in, uint16_t* __restrict__ out, int R, int C) {
  __shared__ float tile[64][65];
  int z = blockIdx.z;
  const float* inp = in + (size_t)z * R * C;
  uint16_t* outp = out + (size_t)z * R * C;
  int r0 = blockIdx.y * 64, c0 = blockIdx.x * 64;
  int tid = threadIdx.x;
  int lr = tid >> 4;           // 0..15
  int lc4 = (tid & 15) * 4;    // 0,4,...,60
#pragma unroll
  for (int p = 0; p < 4; ++p) {
    float4 v = *(const float4*)&inp[(size_t)(r0 + lr + p * 16) * C + c0 + lc4];
    tile[lr + p * 16][lc4 + 0] = v.x;
    tile[lr + p * 16][lc4 + 1] = v.y;
    tile[lr + p * 16][lc4 + 2] = v.z;
    tile[lr + p * 16][lc4 + 3] = v.w;
  }
  __syncthreads();
#pragma unroll
  for (int p = 0; p < 4; ++p) {
    int c = lr + p * 16;
    ushort4 o;
    o.x = f2bf(tile[lc4 + 0][c]);
    o.y = f2bf(tile[lc4 + 1][c]);
    o.z = f2bf(tile[lc4 + 2][c]);
    o.w = f2bf(tile[lc4 + 3][c]);
    *(ushort4*)&outp[(size_t)(c0 + c) * R + r0 + lc4] = o;
  }
}

// ---------------- router: logits, softmax, top-2, per-block partials ----------------
__global__ __launch_bounds__(256) void router_kernel(
    const float* __restrict__ x, const float* __restrict__ gate_w,
    int* __restrict__ topk_idx, float* __restrict__ topk_w,
    float* __restrict__ part_sums, int* __restrict__ part_counts) {
  __shared__ float g[NE * HD];  // [e][h]
  __shared__ float ls[NE];
  __shared__ int   lc[NE];
  int tid = threadIdx.x;
  for (int i = tid; i < NE * HD; i += 256)
    g[(i & 7) * HD + (i >> 3)] = gate_w[i];
  if (tid < NE) { ls[tid] = 0.f; lc[tid] = 0; }
  __syncthreads();
  int wave = tid >> 6, lane = tid & 63;
  float psum[NE];
#pragma unroll
  for (int e = 0; e < NE; ++e) psum[e] = 0.f;

  for (int tt = 0; tt < RTB / 4; ++tt) {
    int t = blockIdx.x * RTB + wave * (RTB / 4) + tt;
    const float* xr = x + (size_t)t * HD;
    float acc[NE];
#pragma unroll
    for (int e = 0; e < NE; ++e) acc[e] = 0.f;
    for (int i = 0; i < HD / 64; ++i) {
      float xv = xr[lane + i * 64];
#pragma unroll
      for (int e = 0; e < NE; ++e) acc[e] += xv * g[e * HD + lane + i * 64];
    }
#pragma unroll
    for (int off = 32; off > 0; off >>= 1)
#pragma unroll
      for (int e = 0; e < NE; ++e) acc[e] += __shfl_down(acc[e], off);
    if (lane == 0) {
      float m = acc[0];
#pragma unroll
      for (int e = 1; e < NE; ++e) m = fmaxf(m, acc[e]);
      float p[NE], s = 0.f;
#pragma unroll
      for (int e = 0; e < NE; ++e) { p[e] = expf(acc[e] - m); s += p[e]; }
      float inv = 1.f / s;
#pragma unroll
      for (int e = 0; e < NE; ++e) { p[e] *= inv; psum[e] += p[e]; }
      int i0 = 0;
#pragma unroll
      for (int e = 1; e < NE; ++e) if (p[e] > p[i0]) i0 = e;
      int i1 = (i0 == 0) ? 1 : 0;
#pragma unroll
      for (int e = 0; e < NE; ++e) if (e != i0 && e != i1 && p[e] > p[i1]) i1 = e;
      float wsum = p[i0] + p[i1];
      topk_idx[t * 2] = i0; topk_idx[t * 2 + 1] = i1;
      topk_w[t * 2] = p[i0] / wsum; topk_w[t * 2 + 1] = p[i1] / wsum;
      atomicAdd(&lc[i0], 1); atomicAdd(&lc[i1], 1);
    }
  }
  if (lane == 0)
#pragma unroll
    for (int e = 0; e < NE; ++e) atomicAdd(&ls[e], psum[e]);
  __syncthreads();
  if (tid < NE) {
    part_sums[blockIdx.x * NE + tid]   = ls[tid];
    part_counts[blockIdx.x * NE + tid] = lc[tid];
  }
}

// ---------------- finalize: reduce partials, offsets, BOTH tile-desc sets, aux ----------------
__global__ __launch_bounds__(64) void finalize_kernel(
    const int* __restrict__ part_counts, const float* __restrict__ part_sums,
    int* __restrict__ offsets, TileDesc* __restrict__ desc, TileDesc* __restrict__ desc256,
    int* __restrict__ ntiles, int* __restrict__ ntiles256, float* __restrict__ aux_out) {
  __shared__ int   csh[NE];
  __shared__ float ssh[NE];
  int tid = threadIdx.x;
  if (tid < NE) {
    int c = 0; float s = 0.f;
    for (int b = 0; b < RNB; ++b) {
      c += part_counts[b * NE + tid];
      s += part_sums[b * NE + tid];
    }
    csh[tid] = c; ssh[tid] = s;
  }
  __syncthreads();
  if (tid == 0) {
    int off = 0, nt = 0, nt2 = 0;
    for (int e = 0; e < NE; ++e) {
      offsets[e] = off;
      int c = csh[e];
      for (int i = 0; i < c; i += 128) {
        int rows = c - i; if (rows > 128) rows = 128;
        desc[nt].e = e; desc[nt].start = off + i; desc[nt].rows = rows; desc[nt].pad = 0;
        nt++;
      }
      for (int i = 0; i < c; i += 256) {
        int rows = c - i; if (rows > 256) rows = 256;
        desc256[nt2].e = e; desc256[nt2].start = off + i; desc256[nt2].rows = rows; desc256[nt2].pad = 0;
        nt2++;
      }
      off += c;
    }
    *ntiles = nt;
    *ntiles256 = nt2;
    float aux = 0.f;
    for (int e = 0; e < NE; ++e) {
      float mean = ssh[e] / (float)T;
      aux += mean * mean;
    }
    *aux_out = (float)NE * aux;
  }
}

// ---------------- scatter: wave-aggregated atomics ----------------
__global__ __launch_bounds__(256) void scatter_kernel(
    const int* __restrict__ topk_idx, const int* __restrict__ offsets,
    int* __restrict__ fill, int* __restrict__ pair_tok, int* __restrict__ tok_pos) {
  int t = blockIdx.x * 256 + threadIdx.x;
  int lane = threadIdx.x & 63;
  unsigned long long below = (lane == 63) ? ~0ull >> 1
                                          : ((1ull << (lane + 1)) - 1) >> 1;
#pragma unroll
  for (int k = 0; k < 2; ++k) {
    int e = topk_idx[t * 2 + k];
    int pos = 0;
    for (int ex = 0; ex < NE; ++ex) {
      unsigned long long m = __ballot(e == ex);
      if (e == ex) {
        int leader = __ffsll((long long)m) - 1;
        int cnt = __popcll(m);
        int base = 0;
        if (lane == leader) base = atomicAdd(&fill[ex], cnt);
        base = __shfl(base, leader);
        pos = base + __popcll(m & below);
      }
    }
    int pp = offsets[e] + pos;
    pair_tok[pp] = t;
    tok_pos[t * 2 + k] = pp;
  }
}

// ============ fc1: 256x256 8-phase pipelined MFMA GEMM (m201/m248 structure) ============
// hidden[p, 0..4095] = relu( xb[pair_tok[p]] @ w1t[e]^T + b1[e] )
// BM=BN=256, BK=64, 8 waves (2M x 4N), per-wave 128x64 out, 128KiB dyn LDS.
// LDS element layout per matrix: [slot2][half2][i2][wave8][lane-linear], st-swizzle
// (XOR row-bit2 into col-byte bit5) applied on BOTH stage-source and ds_read (rule #21).
__global__ __launch_bounds__(512, 2) void moe_fc1_256(
    const uint16_t* __restrict__ xb, const int* __restrict__ pair_tok,
    const uint16_t* __restrict__ w1t, const float* __restrict__ bias,
    uint16_t* __restrict__ hidden, const TileDesc* __restrict__ desc256,
    const int* __restrict__ ntiles256) {
  constexpr int KD = HD;            // 1024
  constexpr int ND = FD;            // 4096
  constexpr int NBC = ND / 256;     // 16 col tiles
  constexpr int NT = KD / 64;       // 16 k-tiles
  constexpr int GRID = NBC * MAXT256;  // 640, % 8 == 0

  extern __shared__ char smem[];
  uint16_t* lds = (uint16_t*)smem;            // 131072 B: A at 0, B at el 32768
  int* rowA = (int*)(smem + 131072);          // 256 ints

  int orig = blockIdx.x;
  int work = (orig & 7) * (GRID / 8) + (orig >> 3);   // XCD-bijective
  int nb = work % NBC;                                 // nb-fastest: A-panel L2-resident
  int mt = work / NBC;
  if (mt >= *ntiles256) return;
  TileDesc d = desc256[mt];

  int tid = threadIdx.x, lane = tid & 63, wave = tid >> 6;
  int wm = wave >> 2, wn = wave & 3;

  if (tid < 256) rowA[tid] = (tid < d.rows) ? pair_tok[d.start + tid] : 0;
  __syncthreads();

  // ---- staging source pointers (pre-swizzled global per rule #21) ----
  int wl8 = wave * 8 + (lane >> 3);                       // staged row (i=0 base)
  int colel = ((lane & 7) << 3) ^ (((lane >> 5) & 1) << 4);  // swz by row-bit2
  const uint16_t* Asrc[2][2];
  const uint16_t* Bsrc[2][2];
#pragma unroll
  for (int h = 0; h < 2; ++h)
#pragma unroll
    for (int i = 0; i < 2; ++i) {
      int lr = h * 128 + i * 64 + wl8;
      Asrc[h][i] = xb + (size_t)rowA[lr] * KD + colel;
      Bsrc[h][i] = w1t + ((size_t)d.e * ND + nb * 256 + lr) * KD + colel;
    }

  auto stage = [&](int slot, int kt) {
    int ko = kt * 64;
#pragma unroll
    for (int h = 0; h < 2; ++h)
#pragma unroll
      for (int i = 0; i < 2; ++i) {
        int dst = slot * 16384 + h * 8192 + i * 4096 + wave * 512;  // elements
        gload_lds16(Asrc[h][i] + ko, &lds[dst]);
        gload_lds16(Bsrc[h][i] + ko, &lds[32768 + dst]);
      }
  };

  // ---- fragment read offset (elements), swizzled ----
  int laneRd = (lane & 15) * 64 + (((lane >> 4) * 8) ^ (((lane >> 2) & 1) << 4));

  f32x4 acc[8][4];
#pragma unroll
  for (int i = 0; i < 8; ++i)
#pragma unroll
    for (int j = 0; j < 4; ++j) acc[i][j] = (f32x4){0.f, 0.f, 0.f, 0.f};

  short8x aq[4][2], b0[2][2], b1[2][2];

  stage(0, 0);
  stage(1, 1);
  asm volatile("s_waitcnt vmcnt(8)" ::: "memory");   // tile0 landed
  SBAR();

  for (int kt = 0; kt < NT; ++kt) {
    int slot = kt & 1;
    int Ab = slot * 16384 + wm * 8192;
    int Bb = 32768 + slot * 16384 + (wn >> 1) * 8192 + (wn & 1) * 4096;

    // ---- Phase 1: quadrant (mh0, n0/1) ----
#pragma unroll
    for (int fm = 0; fm < 4; ++fm)
#pragma unroll
      for (int ks = 0; ks < 2; ++ks)
        aq[fm][ks] = *(const short8x*)&lds[Ab + fm * 1024 + ks * 32 + laneRd];
#pragma unroll
    for (int fn = 0; fn < 2; ++fn)
#pragma unroll
      for (int ks = 0; ks < 2; ++ks)
        b0[fn][ks] = *(const short8x*)&lds[Bb + fn * 1024 + ks * 32 + laneRd];
    SBAR();
    __builtin_amdgcn_s_setprio(1);
#pragma unroll
    for (int fm = 0; fm < 4; ++fm)
#pragma unroll
      for (int fn = 0; fn < 2; ++fn)
#pragma unroll
        for (int ks = 0; ks < 2; ++ks)
          acc[fm][fn] = __builtin_amdgcn_mfma_f32_16x16x32_bf16(aq[fm][ks], b0[fn][ks], acc[fm][fn], 0, 0, 0);
    __builtin_amdgcn_s_setprio(0);
    SBAR();

    // ---- Phase 2: quadrant (mh0, n2/3) ----
#pragma unroll
    for (int fn = 0; fn < 2; ++fn)
#pragma unroll
      for (int ks = 0; ks < 2; ++ks)
        b1[fn][ks] = *(const short8x*)&lds[Bb + (fn + 2) * 1024 + ks * 32 + laneRd];
    SBAR();
    __builtin_amdgcn_s_setprio(1);
#pragma unroll
    for (int fm = 0; fm < 4; ++fm)
#pragma unroll
      for (int fn = 0; fn < 2; ++fn)
#pragma unroll
        for (int ks = 0; ks < 2; ++ks)
          acc[fm][fn + 2] = __builtin_amdgcn_mfma_f32_16x16x32_bf16(aq[fm][ks], b1[fn][ks], acc[fm][fn + 2], 0, 0, 0);
    __builtin_amdgcn_s_setprio(0);
    SBAR();

    // ---- Phase 3: quadrant (mh1, n2/3) ----
#pragma unroll
    for (int fm = 0; fm < 4; ++fm)
#pragma unroll
      for (int ks = 0; ks < 2; ++ks)
        aq[fm][ks] = *(const short8x*)&lds[Ab + 4096 + fm * 1024 + ks * 32 + laneRd];
    SBAR();
    __builtin_amdgcn_s_setprio(1);
#pragma unroll
    for (int fm = 0; fm < 4; ++fm)
#pragma unroll
      for (int fn = 0; fn < 2; ++fn)
#pragma unroll
        for (int ks = 0; ks < 2; ++ks)
          acc[fm + 4][fn + 2] = __builtin_amdgcn_mfma_f32_16x16x32_bf16(aq[fm][ks], b1[fn][ks], acc[fm + 4][fn + 2], 0, 0, 0);
    __builtin_amdgcn_s_setprio(0);
    SBAR();

    // ---- Phase 4: quadrant (mh1, n0/1); stage kt+2 into freed slot; counted vmcnt ----
    if (kt + 2 < NT) {
      stage(slot, kt + 2);
      asm volatile("s_waitcnt vmcnt(8)" ::: "memory");  // tile kt+1 landed; kt+2 in flight
    } else {
      asm volatile("s_waitcnt vmcnt(0)" ::: "memory");
    }
    __builtin_amdgcn_s_setprio(1);
#pragma unroll
    for (int fm = 0; fm < 4; ++fm)
#pragma unroll
      for (int fn = 0; fn < 2; ++fn)
#pragma unroll
        for (int ks = 0; ks < 2; ++ks)
          acc[fm + 4][fn] = __builtin_amdgcn_mfma_f32_16x16x32_bf16(aq[fm][ks], b0[fn][ks], acc[fm + 4][fn], 0, 0, 0);
    __builtin_amdgcn_s_setprio(0);
    SBAR();
  }

  // ---- epilogue: bias + relu + bf16 store ----
  int rq = (lane >> 4) * 4, cl = lane & 15;
  float bv[4];
#pragma unroll
  for (int fn = 0; fn < 4; ++fn)
    bv[fn] = bias[d.e * ND + nb * 256 + wn * 64 + fn * 16 + cl];
#pragma unroll
  for (int fm = 0; fm < 8; ++fm) {
    int rb = wm * 128 + fm * 16 + rq;
#pragma unroll
    for (int fn = 0; fn < 4; ++fn) {
      int col = nb * 256 + wn * 64 + fn * 16 + cl;
#pragma unroll
      for (int q = 0; q < 4; ++q) {
        int r = rb + q;
        if (r < d.rows) {
          float v = fmaxf(acc[fm][fn][q] + bv[fn], 0.f);
          hidden[(size_t)(d.start + r) * ND + col] = f2bf(v);
        }
      }
    }
  }
}

// ---------------- fc2: proven R2 128x128 2-barrier MFMA GEMM ----------------
// pout[rows, HD] = hidden[rows, FD] @ w2t[e][HD, FD]^T + b2[e]
__global__ __launch_bounds__(256) void moe_fc2_128(
    const uint16_t* __restrict__ Abase, const uint16_t* __restrict__ Bw,
    const float* __restrict__ bias, uint16_t* __restrict__ Cout,
    const TileDesc* __restrict__ desc, const int* __restrict__ ntiles) {
  constexpr int KD = FD;  // 4096
  constexpr int ND = HD;  // 1024
  int mt = blockIdx.y;
  if (mt >= *ntiles) return;
  TileDesc d = desc[mt];
  int nb = blockIdx.x;

  __shared__ uint16_t As[128 * 32];
  __shared__ uint16_t Bs[128 * 32];

  int tid = threadIdx.x, lane = tid & 63, wave = tid >> 6;
  int wm = wave >> 1, wn = wave & 1;

  int idx0 = (wave * 2 + 0) * 64 + lane;
  int idx1 = (wave * 2 + 1) * 64 + lane;
  int ar0 = idx0 >> 2, kc0 = idx0 & 3;
  int ar1 = idx1 >> 2, kc1 = idx1 & 3;

  int ra0 = d.start + ar0, ra1 = d.start + ar1;
  const uint16_t* Bbase = Bw + ((size_t)d.e * ND + (size_t)nb * 128) * KD;

  f32x4 acc[4][4];
#pragma unroll
  for (int i = 0; i < 4; ++i)
#pragma unroll
    for (int j = 0; j < 4; ++j) acc[i][j] = (f32x4){0.f, 0.f, 0.f, 0.f};

  for (int kt = 0; kt < KD / 32; ++kt) {
    if (kt) __syncthreads();
    int kb = kt * 32;
    gload_lds16(Abase + (size_t)ra0 * KD + kb + kc0 * 8, &As[(wave * 2 + 0) * 512]);
    gload_lds16(Abase + (size_t)ra1 * KD + kb + kc1 * 8, &As[(wave * 2 + 1) * 512]);
    gload_lds16(Bbase + (size_t)ar0 * KD + kb + kc0 * 8, &Bs[(wave * 2 + 0) * 512]);
    gload_lds16(Bbase + (size_t)ar1 * KD + kb + kc1 * 8, &Bs[(wave * 2 + 1) * 512]);
    __syncthreads();

    short8x af[4], bfr[4];
#pragma unroll
    for (int i = 0; i < 4; ++i)
      af[i] = *(const short8x*)&As[(wm * 64 + i * 16 + (lane & 15)) * 32 + (lane >> 4) * 8];
#pragma unroll
    for (int j = 0; j < 4; ++j)
      bfr[j] = *(const short8x*)&Bs[(wn * 64 + j * 16 + (lane & 15)) * 32 + (lane >> 4) * 8];
#pragma unroll
    for (int i = 0; i < 4; ++i)
#pragma unroll
      for (int j = 0; j < 4; ++j)
        acc[i][j] = __builtin_amdgcn_mfma_f32_16x16x32_bf16(af[i], bfr[j], acc[i][j], 0, 0, 0);
  }

  int rq = (lane >> 4) * 4;
  int cl = lane & 15;
#pragma unroll
  for (int i = 0; i < 4; ++i) {
    int rb = wm * 64 + i * 16 + rq;
#pragma unroll
    for (int j = 0; j < 4; ++j) {
      int col = nb * 128 + wn * 64 + j * 16 + cl;
      float bvv = bias[d.e * ND + col];
#pragma unroll
      for (int q = 0; q < 4; ++q) {
        int r = rb + q;
        if (r < d.rows) {
          float v = acc[i][j][q] + bvv;
          Cout[(size_t)(d.start + r) * ND + col] = f2bf(v);
        }
      }
    }
  }
}

// ---------------- combine: out[t] = w0*po[p0] + w1*po[p1] ----------------
__global__ __launch_bounds__(256) void combine_kernel(
    const uint16_t* __restrict__ po, const int* __restrict__ tok_pos,
    const float* __restrict__ topk_w, float* __restrict__ out) {
  int t = blockIdx.x;
  int c = threadIdx.x * 4;
  int p0 = tok_pos[t * 2], p1 = tok_pos[t * 2 + 1];
  float w0 = topk_w[t * 2], w1 = topk_w[t * 2 + 1];
  ushort4 a = *(const ushort4*)&po[(size_t)p0 * HD + c];
  ushort4 b = *(const ushort4*)&po[(size_t)p1 * HD + c];
  float4 o;
  o.x = w0 * bf2f(a.x) + w1 * bf2f(b.x);
  o.y = w0 * bf2f(a.y) + w1 * bf2f(b.y);
  o.z = w0 * bf2f(a.z) + w1 * bf2f(b.z);
  o.w = w0 * bf2f(a.w) + w1 * bf2f(b.w);
  *(float4*)&out[(size_t)t * HD + c] = o;
}

extern "C" void kernel_launch(void* const* d_in, const int* in_sizes, int n_in,
                              void* d_out, int out_size, void* d_ws, size_t ws_size,
                              hipStream_t stream) {
  const float* x      = (const float*)d_in[0];
  const float* gate_w = (const float*)d_in[1];
  const float* w1     = (const float*)d_in[2];
  const float* b1     = (const float*)d_in[3];
  const float* w2     = (const float*)d_in[4];
  const float* b2     = (const float*)d_in[5];
  float* out = (float*)d_out;
  (void)in_sizes; (void)n_in; (void)out_size; (void)ws_size;

  char* w = (char*)d_ws;
  size_t off = 0;
  auto alloc = [&](size_t bytes) -> void* {
    void* p = w + off;
    off = (off + bytes + 255) & ~(size_t)255;
    return p;
  };
  int*      meta     = (int*)alloc(256);           // fill[8]
  int*      fill     = meta;
  int*      offsets  = (int*)alloc(256);           // offsets[8], ntiles at [8], ntiles256 at [9]
  int*      ntiles   = offsets + 8;
  int*      ntiles256 = offsets + 9;
  TileDesc* desc     = (TileDesc*)alloc(sizeof(TileDesc) * 128);
  TileDesc* desc256  = (TileDesc*)alloc(sizeof(TileDesc) * 64);
  int*      topk_idx = (int*)alloc(sizeof(int) * P);
  float*    topk_w   = (float*)alloc(sizeof(float) * P);
  int*      tok_pos  = (int*)alloc(sizeof(int) * P);
  int*      pair_tok = (int*)alloc(sizeof(int) * PPAD);
  float*    psums    = (float*)alloc(sizeof(float) * RNB * NE);
  int*      pcounts  = (int*)alloc(sizeof(int) * RNB * NE);
  uint16_t* xb       = (uint16_t*)alloc((size_t)T * HD * 2);
  uint16_t* w1t      = (uint16_t*)alloc((size_t)NE * FD * HD * 2);
  uint16_t* w2t      = (uint16_t*)alloc((size_t)NE * HD * FD * 2);
  uint16_t* hidden   = (uint16_t*)alloc((size_t)PPAD * FD * 2);
  uint16_t* pout     = (uint16_t*)alloc((size_t)PPAD * HD * 2);

  hipMemsetAsync(meta, 0, 256, stream);
  cvt_x_kernel<<<(T * HD) / 1024, 256, 0, stream>>>(x, xb);
  transpose_cvt_kernel<<<dim3(FD / 64, HD / 64, NE), 256, 0, stream>>>(w1, w1t, HD, FD);
  transpose_cvt_kernel<<<dim3(HD / 64, FD / 64, NE), 256, 0, stream>>>(w2, w2t, FD, HD);
  router_kernel<<<RNB, 256, 0, stream>>>(x, gate_w, topk_idx, topk_w, psums, pcounts);
  finalize_kernel<<<1, 64, 0, stream>>>(pcounts, psums, offsets, desc, desc256,
                                        ntiles, ntiles256, out + (size_t)T * HD);
  scatter_kernel<<<T / 256, 256, 0, stream>>>(topk_idx, offsets, fill, pair_tok, tok_pos);
  moe_fc1_256<<<(FD / 256) * MAXT256, 512, 131072 + 1024, stream>>>(
      xb, pair_tok, w1t, b1, hidden, desc256, ntiles256);
  moe_fc2_128<<<dim3(HD / 128, MAXTILES), 256, 0, stream>>>(
      hidden, w2t, b2, pout, desc, ntiles);
  combine_kernel<<<T, 256, 0, stream>>>(pout, tok_pos, topk_w, out);
}

// Round 5
// 417.243 us; speedup vs baseline: 1.0170x; 1.0170x over previous
//
#include <hip/hip_runtime.h>
#include <hip/hip_bf16.h>
#include <cstdint>

#define AS1 __attribute__((address_space(1)))
#define AS3 __attribute__((address_space(3)))
#define SBAR() asm volatile("s_barrier" ::: "memory")

typedef __attribute__((ext_vector_type(8))) short short8x;   // 8 bf16 (4 VGPRs)
typedef __attribute__((ext_vector_type(4))) float f32x4;     // MFMA C/D

static constexpr int T    = 4096;   // tokens
static constexpr int HD   = 1024;   // hidden dim
static constexpr int FD   = 4096;   // ffn dim
static constexpr int NE   = 8;      // experts
static constexpr int P    = T * 2;  // routed pairs (top-2)
static constexpr int PPAD = P + 256;
static constexpr int MAXT256 = P / 256 + NE;  // 40 (256-row tiles)
static constexpr int RTB  = 16;
static constexpr int RNB  = T / RTB;  // 256 router blocks

struct TileDesc { int e; int start; int rows; int pad; };

__device__ __forceinline__ uint16_t f2bf(float f) {
  uint32_t u = __builtin_bit_cast(uint32_t, f);
  u += 0x7FFFu + ((u >> 16) & 1u);
  return (uint16_t)(u >> 16);
}
__device__ __forceinline__ float bf2f(uint16_t b) {
  uint32_t u = ((uint32_t)b) << 16;
  return __builtin_bit_cast(float, u);
}

__device__ __forceinline__ void gload_lds16(const void* g, void* l) {
  __builtin_amdgcn_global_load_lds((const AS1 uint32_t*)g, (AS3 uint32_t*)l, 16, 0, 0);
}

// raw LDS read: compiler cannot see the dependency -> no auto vmcnt(0) drain.
// MUST pair with explicit s_waitcnt lgkmcnt(0) + sched_barrier(0) (rule #18).
__device__ __forceinline__ short8x ds128(uint32_t addr) {
  short8x r;
  asm volatile("ds_read_b128 %0, %1" : "=v"(r) : "v"(addr));
  return r;
}

// ---------------- x fp32 -> bf16 ----------------
__global__ __launch_bounds__(256) void cvt_x_kernel(const float* __restrict__ x,
                                                    uint16_t* __restrict__ xb) {
  size_t i = ((size_t)blockIdx.x * 256 + threadIdx.x) * 4;
  float4 v = *(const float4*)&x[i];
  ushort4 o;
  o.x = f2bf(v.x); o.y = f2bf(v.y); o.z = f2bf(v.z); o.w = f2bf(v.w);
  *(ushort4*)&xb[i] = o;
}

// ------------- transpose + cvt: in [z][R][C] f32 -> out [z][C][R] bf16 -------------
__global__ __launch_bounds__(256) void transpose_cvt_kernel(
    const float* __restrict__ in, uint16_t* __restrict__ out, int R, int C) {
  __shared__ float tile[64][65];
  int z = blockIdx.z;
  const float* inp = in + (size_t)z * R * C;
  uint16_t* outp = out + (size_t)z * R * C;
  int r0 = blockIdx.y * 64, c0 = blockIdx.x * 64;
  int tid = threadIdx.x;
  int lr = tid >> 4;
  int lc4 = (tid & 15) * 4;
#pragma unroll
  for (int p = 0; p < 4; ++p) {
    float4 v = *(const float4*)&inp[(size_t)(r0 + lr + p * 16) * C + c0 + lc4];
    tile[lr + p * 16][lc4 + 0] = v.x;
    tile[lr + p * 16][lc4 + 1] = v.y;
    tile[lr + p * 16][lc4 + 2] = v.z;
    tile[lr + p * 16][lc4 + 3] = v.w;
  }
  __syncthreads();
#pragma unroll
  for (int p = 0; p < 4; ++p) {
    int c = lr + p * 16;
    ushort4 o;
    o.x = f2bf(tile[lc4 + 0][c]);
    o.y = f2bf(tile[lc4 + 1][c]);
    o.z = f2bf(tile[lc4 + 2][c]);
    o.w = f2bf(tile[lc4 + 3][c]);
    *(ushort4*)&outp[(size_t)(c0 + c) * R + r0 + lc4] = o;
  }
}

// ---------------- router ----------------
__global__ __launch_bounds__(256) void router_kernel(
    const float* __restrict__ x, const float* __restrict__ gate_w,
    int* __restrict__ topk_idx, float* __restrict__ topk_w,
    float* __restrict__ part_sums, int* __restrict__ part_counts) {
  __shared__ float g[NE * HD];
  __shared__ float ls[NE];
  __shared__ int   lc[NE];
  int tid = threadIdx.x;
  for (int i = tid; i < NE * HD; i += 256)
    g[(i & 7) * HD + (i >> 3)] = gate_w[i];
  if (tid < NE) { ls[tid] = 0.f; lc[tid] = 0; }
  __syncthreads();
  int wave = tid >> 6, lane = tid & 63;
  float psum[NE];
#pragma unroll
  for (int e = 0; e < NE; ++e) psum[e] = 0.f;

  for (int tt = 0; tt < RTB / 4; ++tt) {
    int t = blockIdx.x * RTB + wave * (RTB / 4) + tt;
    const float* xr = x + (size_t)t * HD;
    float acc[NE];
#pragma unroll
    for (int e = 0; e < NE; ++e) acc[e] = 0.f;
    for (int i = 0; i < HD / 64; ++i) {
      float xv = xr[lane + i * 64];
#pragma unroll
      for (int e = 0; e < NE; ++e) acc[e] += xv * g[e * HD + lane + i * 64];
    }
#pragma unroll
    for (int off = 32; off > 0; off >>= 1)
#pragma unroll
      for (int e = 0; e < NE; ++e) acc[e] += __shfl_down(acc[e], off);
    if (lane == 0) {
      float m = acc[0];
#pragma unroll
      for (int e = 1; e < NE; ++e) m = fmaxf(m, acc[e]);
      float p[NE], s = 0.f;
#pragma unroll
      for (int e = 0; e < NE; ++e) { p[e] = expf(acc[e] - m); s += p[e]; }
      float inv = 1.f / s;
#pragma unroll
      for (int e = 0; e < NE; ++e) { p[e] *= inv; psum[e] += p[e]; }
      int i0 = 0;
#pragma unroll
      for (int e = 1; e < NE; ++e) if (p[e] > p[i0]) i0 = e;
      int i1 = (i0 == 0) ? 1 : 0;
#pragma unroll
      for (int e = 0; e < NE; ++e) if (e != i0 && e != i1 && p[e] > p[i1]) i1 = e;
      float wsum = p[i0] + p[i1];
      topk_idx[t * 2] = i0; topk_idx[t * 2 + 1] = i1;
      topk_w[t * 2] = p[i0] / wsum; topk_w[t * 2 + 1] = p[i1] / wsum;
      atomicAdd(&lc[i0], 1); atomicAdd(&lc[i1], 1);
    }
  }
  if (lane == 0)
#pragma unroll
    for (int e = 0; e < NE; ++e) atomicAdd(&ls[e], psum[e]);
  __syncthreads();
  if (tid < NE) {
    part_sums[blockIdx.x * NE + tid]   = ls[tid];
    part_counts[blockIdx.x * NE + tid] = lc[tid];
  }
}

// ---------------- finalize ----------------
__global__ __launch_bounds__(64) void finalize_kernel(
    const int* __restrict__ part_counts, const float* __restrict__ part_sums,
    int* __restrict__ offsets, TileDesc* __restrict__ desc256,
    int* __restrict__ ntiles256, float* __restrict__ aux_out) {
  __shared__ int   csh[NE];
  __shared__ float ssh[NE];
  int tid = threadIdx.x;
  if (tid < NE) {
    int c = 0; float s = 0.f;
    for (int b = 0; b < RNB; ++b) {
      c += part_counts[b * NE + tid];
      s += part_sums[b * NE + tid];
    }
    csh[tid] = c; ssh[tid] = s;
  }
  __syncthreads();
  if (tid == 0) {
    int off = 0, nt2 = 0;
    for (int e = 0; e < NE; ++e) {
      offsets[e] = off;
      int c = csh[e];
      for (int i = 0; i < c; i += 256) {
        int rows = c - i; if (rows > 256) rows = 256;
        desc256[nt2].e = e; desc256[nt2].start = off + i; desc256[nt2].rows = rows;
        desc256[nt2].pad = 0; nt2++;
      }
      off += c;
    }
    *ntiles256 = nt2;
    float aux = 0.f;
    for (int e = 0; e < NE; ++e) {
      float mean = ssh[e] / (float)T;
      aux += mean * mean;
    }
    *aux_out = (float)NE * aux;
  }
}

// ---------------- scatter ----------------
__global__ __launch_bounds__(256) void scatter_kernel(
    const int* __restrict__ topk_idx, const int* __restrict__ offsets,
    int* __restrict__ fill, int* __restrict__ pair_tok, int* __restrict__ tok_pos) {
  int t = blockIdx.x * 256 + threadIdx.x;
  int lane = threadIdx.x & 63;
  unsigned long long below = (lane == 63) ? ~0ull >> 1
                                          : ((1ull << (lane + 1)) - 1) >> 1;
#pragma unroll
  for (int k = 0; k < 2; ++k) {
    int e = topk_idx[t * 2 + k];
    int pos = 0;
    for (int ex = 0; ex < NE; ++ex) {
      unsigned long long m = __ballot(e == ex);
      if (e == ex) {
        int leader = __ffsll((long long)m) - 1;
        int cnt = __popcll(m);
        int base = 0;
        if (lane == leader) base = atomicAdd(&fill[ex], cnt);
        base = __shfl(base, leader);
        pos = base + __popcll(m & below);
      }
    }
    int pp = offsets[e] + pos;
    pair_tok[pp] = t;
    tok_pos[t * 2 + k] = pp;
  }
}

// ============ unified 256x256 8-phase MFMA GEMM (m201 structure, faithful) ============
// C[rows,ND] = A[rows,KD] * Bw[e][ND,KD]^T (+bias, opt relu)
// BM=BN=256, BK=64, 8 waves (2M x 4N), per-wave 128x64. 128 KiB LDS, 2-slot dbuf.
// 3-bit XOR swizzle: LDS slot s of row r holds source 16B-slot s^(r&7); applied on
// stage SOURCE address and on ds_read address (both-sides, rule #21).
// ds_read via inline asm (no compiler vmcnt drain); counted vmcnt(LPT); lgkmcnt(0)
// + sched_barrier(0) before each MFMA cluster (rule #18).
template <int KD, int ND, bool GATHER, bool RELU>
__global__ __launch_bounds__(512, 2) void moe_gemm8(
    const uint16_t* __restrict__ A, const int* __restrict__ pair_tok,
    const uint16_t* __restrict__ Bw, const float* __restrict__ bias,
    uint16_t* __restrict__ C, const TileDesc* __restrict__ desc,
    const int* __restrict__ nt_ptr) {
  constexpr int NBC   = ND / 256;
  constexpr int NT    = KD / 64;
  constexpr int ASLOT = 16384;          // elements per slot (256 rows x 64)
  constexpr int BOFF  = 2 * ASLOT;      // B region start (elements)
  constexpr int GRIDT = NBC * MAXT256;  // % 8 == 0

  extern __shared__ char smem[];
  uint16_t* lds = (uint16_t*)smem;                 // A: [0,32768) el, B: [32768,65536)
  int* rowA = (int*)(smem + 131072);

  int orig = blockIdx.x;
  int work = (orig & 7) * (GRIDT / 8) + (orig >> 3);   // XCD-bijective
  int nb = work % NBC;
  int mt = work / NBC;
  if (mt >= *nt_ptr) return;
  TileDesc d = desc[mt];

  int tid = threadIdx.x, lane = tid & 63, wave = tid >> 6;
  int wm = wave >> 2, wn = wave & 3;

  if constexpr (GATHER) {
    if (tid < 256) rowA[tid] = (tid < d.rows) ? pair_tok[d.start + tid] : 0;
    __syncthreads();
  }

  // staging: lane covers row (i*64 + wave*8 + lane>>3), 16B slot (lane&7), source
  // slot pre-swizzled by row&7 = lane>>3.
  int wl8 = wave * 8 + (lane >> 3);
  int colel = (((lane & 7) ^ (lane >> 3)) << 3);
  const uint16_t* Asrc[4];
  const uint16_t* Bsrc[4];
#pragma unroll
  for (int i = 0; i < 4; ++i) {
    int r = i * 64 + wl8;
    int gr;
    if constexpr (GATHER) gr = rowA[r]; else gr = d.start + r;
    Asrc[i] = A + (size_t)gr * KD + colel;
    Bsrc[i] = Bw + ((size_t)d.e * ND + nb * 256 + r) * KD + colel;
  }

  auto stage = [&](int slot, int kt) {
    int ko = kt * 64;
#pragma unroll
    for (int i = 0; i < 4; ++i)
      gload_lds16(Asrc[i] + ko, &lds[slot * ASLOT + i * 4096 + wave * 512]);
#pragma unroll
    for (int j = 0; j < 4; ++j)
      gload_lds16(Bsrc[j] + ko, &lds[BOFF + slot * ASLOT + j * 4096 + wave * 512]);
  };

  // fragment read: row = base + (lane&15) (row&7 = lane&7), want source slot
  // (lane>>4) + 4*ks -> read LDS slot xor (lane&7).
  uint32_t ldsu = (uint32_t)(uintptr_t)(AS3 char*)smem;
  int rd0 = (lane & 15) * 64 + ((((lane >> 4)) ^ (lane & 7)) << 3);
  int rd1 = (lane & 15) * 64 + ((((lane >> 4) | 4) ^ (lane & 7)) << 3);
  uint32_t aA0 = ldsu + (uint32_t)(wm * 8192 + rd0) * 2;
  uint32_t aA1 = ldsu + (uint32_t)(wm * 8192 + rd1) * 2;
  uint32_t aB0 = ldsu + (uint32_t)(BOFF + wn * 4096 + rd0) * 2;
  uint32_t aB1 = ldsu + (uint32_t)(BOFF + wn * 4096 + rd1) * 2;

  f32x4 acc[8][4];
#pragma unroll
  for (int i = 0; i < 8; ++i)
#pragma unroll
    for (int j = 0; j < 4; ++j) acc[i][j] = (f32x4){0.f, 0.f, 0.f, 0.f};

  short8x aq[4][2], bA[2][2], bB[2][2];

  stage(0, 0);
  stage(1, 1);
  asm volatile("s_waitcnt vmcnt(8)" ::: "memory");   // tile 0 landed, tile 1 in flight
  SBAR();

  for (int kt = 0; kt < NT; ++kt) {
    int slot = kt & 1;
    uint32_t sa = slot ? 32768u : 0u;   // ASLOT*2 bytes

    // ---- Phase 1: read A-half0 + B n0/1; MFMA (mh0, n0/1) ----
#pragma unroll
    for (int fm = 0; fm < 4; ++fm) {
      aq[fm][0] = ds128(aA0 + sa + fm * 2048);
      aq[fm][1] = ds128(aA1 + sa + fm * 2048);
    }
#pragma unroll
    for (int fn = 0; fn < 2; ++fn) {
      bA[fn][0] = ds128(aB0 + sa + fn * 2048);
      bA[fn][1] = ds128(aB1 + sa + fn * 2048);
    }
    SBAR();
    asm volatile("s_waitcnt lgkmcnt(0)" ::: "memory");
    __builtin_amdgcn_sched_barrier(0);
    __builtin_amdgcn_s_setprio(1);
#pragma unroll
    for (int fm = 0; fm < 4; ++fm)
#pragma unroll
      for (int fn = 0; fn < 2; ++fn) {
        acc[fm][fn] = __builtin_amdgcn_mfma_f32_16x16x32_bf16(aq[fm][0], bA[fn][0], acc[fm][fn], 0, 0, 0);
        acc[fm][fn] = __builtin_amdgcn_mfma_f32_16x16x32_bf16(aq[fm][1], bA[fn][1], acc[fm][fn], 0, 0, 0);
      }
    __builtin_amdgcn_s_setprio(0);
    SBAR();

    // ---- Phase 2: read B n2/3; MFMA (mh0, n2/3) ----
#pragma unroll
    for (int fn = 0; fn < 2; ++fn) {
      bB[fn][0] = ds128(aB0 + sa + (fn + 2) * 2048);
      bB[fn][1] = ds128(aB1 + sa + (fn + 2) * 2048);
    }
    SBAR();
    asm volatile("s_waitcnt lgkmcnt(0)" ::: "memory");
    __builtin_amdgcn_sched_barrier(0);
    __builtin_amdgcn_s_setprio(1);
#pragma unroll
    for (int fm = 0; fm < 4; ++fm)
#pragma unroll
      for (int fn = 0; fn < 2; ++fn) {
        acc[fm][fn + 2] = __builtin_amdgcn_mfma_f32_16x16x32_bf16(aq[fm][0], bB[fn][0], acc[fm][fn + 2], 0, 0, 0);
        acc[fm][fn + 2] = __builtin_amdgcn_mfma_f32_16x16x32_bf16(aq[fm][1], bB[fn][1], acc[fm][fn + 2], 0, 0, 0);
      }
    __builtin_amdgcn_s_setprio(0);
    SBAR();

    // ---- Phase 3: read A-half1; MFMA (mh1, n2/3) ----
#pragma unroll
    for (int fm = 0; fm < 4; ++fm) {
      aq[fm][0] = ds128(aA0 + sa + 8192 + fm * 2048);
      aq[fm][1] = ds128(aA1 + sa + 8192 + fm * 2048);
    }
    SBAR();
    asm volatile("s_waitcnt lgkmcnt(0)" ::: "memory");
    __builtin_amdgcn_sched_barrier(0);
    __builtin_amdgcn_s_setprio(1);
#pragma unroll
    for (int fm = 0; fm < 4; ++fm)
#pragma unroll
      for (int fn = 0; fn < 2; ++fn) {
        acc[fm + 4][fn + 2] = __builtin_amdgcn_mfma_f32_16x16x32_bf16(aq[fm][0], bB[fn][0], acc[fm + 4][fn + 2], 0, 0, 0);
        acc[fm + 4][fn + 2] = __builtin_amdgcn_mfma_f32_16x16x32_bf16(aq[fm][1], bB[fn][1], acc[fm + 4][fn + 2], 0, 0, 0);
      }
    __builtin_amdgcn_s_setprio(0);
    SBAR();

    // ---- Phase 4: stage kt+2 (freed slot); MFMA (mh1, n0/1); counted vmcnt ----
    bool more = (kt + 2 < NT);
    if (more) stage(slot, kt + 2);
    __builtin_amdgcn_s_setprio(1);
#pragma unroll
    for (int fm = 0; fm < 4; ++fm)
#pragma unroll
      for (int fn = 0; fn < 2; ++fn) {
        acc[fm + 4][fn] = __builtin_amdgcn_mfma_f32_16x16x32_bf16(aq[fm][0], bA[fn][0], acc[fm + 4][fn], 0, 0, 0);
        acc[fm + 4][fn] = __builtin_amdgcn_mfma_f32_16x16x32_bf16(aq[fm][1], bA[fn][1], acc[fm + 4][fn], 0, 0, 0);
      }
    __builtin_amdgcn_s_setprio(0);
    if (more) asm volatile("s_waitcnt vmcnt(8)" ::: "memory");  // tile kt+1 landed
    else      asm volatile("s_waitcnt vmcnt(0)" ::: "memory");
    SBAR();
  }

  // ---- epilogue ----
  int rq = (lane >> 4) * 4, cl = lane & 15;
  float bv[4];
#pragma unroll
  for (int fn = 0; fn < 4; ++fn)
    bv[fn] = bias[d.e * ND + nb * 256 + wn * 64 + fn * 16 + cl];
#pragma unroll
  for (int fm = 0; fm < 8; ++fm) {
    int rb = wm * 128 + fm * 16 + rq;
#pragma unroll
    for (int fn = 0; fn < 4; ++fn) {
      int col = nb * 256 + wn * 64 + fn * 16 + cl;
#pragma unroll
      for (int q = 0; q < 4; ++q) {
        int r = rb + q;
        if (r < d.rows) {
          float v = acc[fm][fn][q] + bv[fn];
          if constexpr (RELU) v = fmaxf(v, 0.f);
          C[(size_t)(d.start + r) * ND + col] = f2bf(v);
        }
      }
    }
  }
}

// ---------------- combine ----------------
__global__ __launch_bounds__(256) void combine_kernel(
    const uint16_t* __restrict__ po, const int* __restrict__ tok_pos,
    const float* __restrict__ topk_w, float* __restrict__ out) {
  int t = blockIdx.x;
  int c = threadIdx.x * 4;
  int p0 = tok_pos[t * 2], p1 = tok_pos[t * 2 + 1];
  float w0 = topk_w[t * 2], w1 = topk_w[t * 2 + 1];
  ushort4 a = *(const ushort4*)&po[(size_t)p0 * HD + c];
  ushort4 b = *(const ushort4*)&po[(size_t)p1 * HD + c];
  float4 o;
  o.x = w0 * bf2f(a.x) + w1 * bf2f(b.x);
  o.y = w0 * bf2f(a.y) + w1 * bf2f(b.y);
  o.z = w0 * bf2f(a.z) + w1 * bf2f(b.z);
  o.w = w0 * bf2f(a.w) + w1 * bf2f(b.w);
  *(float4*)&out[(size_t)t * HD + c] = o;
}

extern "C" void kernel_launch(void* const* d_in, const int* in_sizes, int n_in,
                              void* d_out, int out_size, void* d_ws, size_t ws_size,
                              hipStream_t stream) {
  const float* x      = (const float*)d_in[0];
  const float* gate_w = (const float*)d_in[1];
  const float* w1     = (const float*)d_in[2];
  const float* b1     = (const float*)d_in[3];
  const float* w2     = (const float*)d_in[4];
  const float* b2     = (const float*)d_in[5];
  float* out = (float*)d_out;
  (void)in_sizes; (void)n_in; (void)out_size; (void)ws_size;

  char* w = (char*)d_ws;
  size_t off = 0;
  auto alloc = [&](size_t bytes) -> void* {
    void* p = w + off;
    off = (off + bytes + 255) & ~(size_t)255;
    return p;
  };
  int*      meta      = (int*)alloc(256);
  int*      fill      = meta;
  int*      offsets   = (int*)alloc(256);
  int*      ntiles256 = offsets + 8;
  TileDesc* desc256   = (TileDesc*)alloc(sizeof(TileDesc) * 64);
  int*      topk_idx  = (int*)alloc(sizeof(int) * P);
  float*    topk_w    = (float*)alloc(sizeof(float) * P);
  int*      tok_pos   = (int*)alloc(sizeof(int) * P);
  int*      pair_tok  = (int*)alloc(sizeof(int) * PPAD);
  float*    psums     = (float*)alloc(sizeof(float) * RNB * NE);
  int*      pcounts   = (int*)alloc(sizeof(int) * RNB * NE);
  uint16_t* xb        = (uint16_t*)alloc((size_t)T * HD * 2);
  uint16_t* w1t       = (uint16_t*)alloc((size_t)NE * FD * HD * 2);
  uint16_t* w2t       = (uint16_t*)alloc((size_t)NE * HD * FD * 2);
  uint16_t* hidden    = (uint16_t*)alloc((size_t)PPAD * FD * 2);
  uint16_t* pout      = (uint16_t*)alloc((size_t)PPAD * HD * 2);

  constexpr int GLDS = 131072 + 1024;

  hipMemsetAsync(meta, 0, 256, stream);
  cvt_x_kernel<<<(T * HD) / 1024, 256, 0, stream>>>(x, xb);
  transpose_cvt_kernel<<<dim3(FD / 64, HD / 64, NE), 256, 0, stream>>>(w1, w1t, HD, FD);
  transpose_cvt_kernel<<<dim3(HD / 64, FD / 64, NE), 256, 0, stream>>>(w2, w2t, FD, HD);
  router_kernel<<<RNB, 256, 0, stream>>>(x, gate_w, topk_idx, topk_w, psums, pcounts);
  finalize_kernel<<<1, 64, 0, stream>>>(pcounts, psums, offsets, desc256, ntiles256,
                                        out + (size_t)T * HD);
  scatter_kernel<<<T / 256, 256, 0, stream>>>(topk_idx, offsets, fill, pair_tok, tok_pos);
  moe_gemm8<HD, FD, true, true><<<(FD / 256) * MAXT256, 512, GLDS, stream>>>(
      xb, pair_tok, w1t, b1, hidden, desc256, ntiles256);
  moe_gemm8<FD, HD, false, false><<<(HD / 256) * MAXT256, 512, GLDS, stream>>>(
      hidden, nullptr, w2t, b2, pout, desc256, ntiles256);
  combine_kernel<<<T, 256, 0, stream>>>(pout, tok_pos, topk_w, out);
}

// Round 6
// 412.084 us; speedup vs baseline: 1.0298x; 1.0125x over previous
//
#include <hip/hip_runtime.h>
#include <hip/hip_bf16.h>
#include <cstdint>

#define AS1 __attribute__((address_space(1)))
#define AS3 __attribute__((address_space(3)))
#define SBAR() asm volatile("s_barrier" ::: "memory")
#define LGKM_SB(n) do { asm volatile("s_waitcnt lgkmcnt(" #n ")" ::: "memory"); \
                        __builtin_amdgcn_sched_barrier(0); } while (0)

typedef __attribute__((ext_vector_type(8))) short short8x;   // 8 bf16 (4 VGPRs)
typedef __attribute__((ext_vector_type(4))) float f32x4;     // MFMA C/D

static constexpr int T    = 4096;
static constexpr int HD   = 1024;
static constexpr int FD   = 4096;
static constexpr int NE   = 8;
static constexpr int P    = T * 2;
static constexpr int PPAD = P + 256;
static constexpr int MAXT256 = P / 256 + NE;  // 40
static constexpr int MAXT128 = P / 128 + NE;  // 72
static constexpr int RTB  = 16;
static constexpr int RNB  = T / RTB;

struct TileDesc { int e; int start; int rows; int pad; };

__device__ __forceinline__ uint16_t f2bf(float f) {
  uint32_t u = __builtin_bit_cast(uint32_t, f);
  u += 0x7FFFu + ((u >> 16) & 1u);
  return (uint16_t)(u >> 16);
}
__device__ __forceinline__ float bf2f(uint16_t b) {
  uint32_t u = ((uint32_t)b) << 16;
  return __builtin_bit_cast(float, u);
}
__device__ __forceinline__ void gload_lds16(const void* g, void* l) {
  __builtin_amdgcn_global_load_lds((const AS1 uint32_t*)g, (AS3 uint32_t*)l, 16, 0, 0);
}
__device__ __forceinline__ short8x ds128(uint32_t addr) {
  short8x r;
  asm volatile("ds_read_b128 %0, %1" : "=v"(r) : "v"(addr));
  return r;
}

// ---------------- x fp32 -> bf16 ----------------
__global__ __launch_bounds__(256) void cvt_x_kernel(const float* __restrict__ x,
                                                    uint16_t* __restrict__ xb) {
  size_t i = ((size_t)blockIdx.x * 256 + threadIdx.x) * 4;
  float4 v = *(const float4*)&x[i];
  ushort4 o;
  o.x = f2bf(v.x); o.y = f2bf(v.y); o.z = f2bf(v.z); o.w = f2bf(v.w);
  *(ushort4*)&xb[i] = o;
}

// ------------- transpose + cvt: in [z][R][C] f32 -> out [z][C][R] bf16 -------------
__global__ __launch_bounds__(256) void transpose_cvt_kernel(
    const float* __restrict__ in, uint16_t* __restrict__ out, int R, int C) {
  __shared__ float tile[64][65];
  int z = blockIdx.z;
  const float* inp = in + (size_t)z * R * C;
  uint16_t* outp = out + (size_t)z * R * C;
  int r0 = blockIdx.y * 64, c0 = blockIdx.x * 64;
  int tid = threadIdx.x;
  int lr = tid >> 4;
  int lc4 = (tid & 15) * 4;
#pragma unroll
  for (int p = 0; p < 4; ++p) {
    float4 v = *(const float4*)&inp[(size_t)(r0 + lr + p * 16) * C + c0 + lc4];
    tile[lr + p * 16][lc4 + 0] = v.x;
    tile[lr + p * 16][lc4 + 1] = v.y;
    tile[lr + p * 16][lc4 + 2] = v.z;
    tile[lr + p * 16][lc4 + 3] = v.w;
  }
  __syncthreads();
#pragma unroll
  for (int p = 0; p < 4; ++p) {
    int c = lr + p * 16;
    ushort4 o;
    o.x = f2bf(tile[lc4 + 0][c]);
    o.y = f2bf(tile[lc4 + 1][c]);
    o.z = f2bf(tile[lc4 + 2][c]);
    o.w = f2bf(tile[lc4 + 3][c]);
    *(ushort4*)&outp[(size_t)(c0 + c) * R + r0 + lc4] = o;
  }
}

// ---------------- router ----------------
__global__ __launch_bounds__(256) void router_kernel(
    const float* __restrict__ x, const float* __restrict__ gate_w,
    int* __restrict__ topk_idx, float* __restrict__ topk_w,
    float* __restrict__ part_sums, int* __restrict__ part_counts) {
  __shared__ float g[NE * HD];
  __shared__ float ls[NE];
  __shared__ int   lc[NE];
  int tid = threadIdx.x;
  for (int i = tid; i < NE * HD; i += 256)
    g[(i & 7) * HD + (i >> 3)] = gate_w[i];
  if (tid < NE) { ls[tid] = 0.f; lc[tid] = 0; }
  __syncthreads();
  int wave = tid >> 6, lane = tid & 63;
  float psum[NE];
#pragma unroll
  for (int e = 0; e < NE; ++e) psum[e] = 0.f;

  for (int tt = 0; tt < RTB / 4; ++tt) {
    int t = blockIdx.x * RTB + wave * (RTB / 4) + tt;
    const float* xr = x + (size_t)t * HD;
    float acc[NE];
#pragma unroll
    for (int e = 0; e < NE; ++e) acc[e] = 0.f;
    for (int i = 0; i < HD / 64; ++i) {
      float xv = xr[lane + i * 64];
#pragma unroll
      for (int e = 0; e < NE; ++e) acc[e] += xv * g[e * HD + lane + i * 64];
    }
#pragma unroll
    for (int off = 32; off > 0; off >>= 1)
#pragma unroll
      for (int e = 0; e < NE; ++e) acc[e] += __shfl_down(acc[e], off);
    if (lane == 0) {
      float m = acc[0];
#pragma unroll
      for (int e = 1; e < NE; ++e) m = fmaxf(m, acc[e]);
      float p[NE], s = 0.f;
#pragma unroll
      for (int e = 0; e < NE; ++e) { p[e] = expf(acc[e] - m); s += p[e]; }
      float inv = 1.f / s;
#pragma unroll
      for (int e = 0; e < NE; ++e) { p[e] *= inv; psum[e] += p[e]; }
      int i0 = 0;
#pragma unroll
      for (int e = 1; e < NE; ++e) if (p[e] > p[i0]) i0 = e;
      int i1 = (i0 == 0) ? 1 : 0;
#pragma unroll
      for (int e = 0; e < NE; ++e) if (e != i0 && e != i1 && p[e] > p[i1]) i1 = e;
      float wsum = p[i0] + p[i1];
      topk_idx[t * 2] = i0; topk_idx[t * 2 + 1] = i1;
      topk_w[t * 2] = p[i0] / wsum; topk_w[t * 2 + 1] = p[i1] / wsum;
      atomicAdd(&lc[i0], 1); atomicAdd(&lc[i1], 1);
    }
  }
  if (lane == 0)
#pragma unroll
    for (int e = 0; e < NE; ++e) atomicAdd(&ls[e], psum[e]);
  __syncthreads();
  if (tid < NE) {
    part_sums[blockIdx.x * NE + tid]   = ls[tid];
    part_counts[blockIdx.x * NE + tid] = lc[tid];
  }
}

// ---------------- finalize: both desc sets ----------------
__global__ __launch_bounds__(64) void finalize_kernel(
    const int* __restrict__ part_counts, const float* __restrict__ part_sums,
    int* __restrict__ offsets, TileDesc* __restrict__ desc256, TileDesc* __restrict__ desc128,
    int* __restrict__ ntiles256, int* __restrict__ ntiles128, float* __restrict__ aux_out) {
  __shared__ int   csh[NE];
  __shared__ float ssh[NE];
  int tid = threadIdx.x;
  if (tid < NE) {
    int c = 0; float s = 0.f;
    for (int b = 0; b < RNB; ++b) {
      c += part_counts[b * NE + tid];
      s += part_sums[b * NE + tid];
    }
    csh[tid] = c; ssh[tid] = s;
  }
  __syncthreads();
  if (tid == 0) {
    int off = 0, n2 = 0, n1 = 0;
    for (int e = 0; e < NE; ++e) {
      offsets[e] = off;
      int c = csh[e];
      for (int i = 0; i < c; i += 256) {
        int rows = c - i; if (rows > 256) rows = 256;
        desc256[n2].e = e; desc256[n2].start = off + i; desc256[n2].rows = rows;
        desc256[n2].pad = 0; n2++;
      }
      for (int i = 0; i < c; i += 128) {
        int rows = c - i; if (rows > 128) rows = 128;
        desc128[n1].e = e; desc128[n1].start = off + i; desc128[n1].rows = rows;
        desc128[n1].pad = 0; n1++;
      }
      off += c;
    }
    *ntiles256 = n2;
    *ntiles128 = n1;
    float aux = 0.f;
    for (int e = 0; e < NE; ++e) {
      float mean = ssh[e] / (float)T;
      aux += mean * mean;
    }
    *aux_out = (float)NE * aux;
  }
}

// ---------------- scatter ----------------
__global__ __launch_bounds__(256) void scatter_kernel(
    const int* __restrict__ topk_idx, const int* __restrict__ offsets,
    int* __restrict__ fill, int* __restrict__ pair_tok, int* __restrict__ tok_pos) {
  int t = blockIdx.x * 256 + threadIdx.x;
  int lane = threadIdx.x & 63;
  unsigned long long below = (lane == 63) ? ~0ull >> 1
                                          : ((1ull << (lane + 1)) - 1) >> 1;
#pragma unroll
  for (int k = 0; k < 2; ++k) {
    int e = topk_idx[t * 2 + k];
    int pos = 0;
    for (int ex = 0; ex < NE; ++ex) {
      unsigned long long m = __ballot(e == ex);
      if (e == ex) {
        int leader = __ffsll((long long)m) - 1;
        int cnt = __popcll(m);
        int base = 0;
        if (lane == leader) base = atomicAdd(&fill[ex], cnt);
        base = __shfl(base, leader);
        pos = base + __popcll(m & below);
      }
    }
    int pp = offsets[e] + pos;
    pair_tok[pp] = t;
    tok_pos[t * 2 + k] = pp;
  }
}

// ============ BMx256 pipelined MFMA GEMM, counted-lgkmcnt ladders ============
// C[rows,ND] = A[rows,KD] * Bw[e][ND,KD]^T (+bias, opt relu)
// BN=256, BK=64, 8 waves (2M x 4N); per-wave (BM/2)x64 output.
// 3-bit XOR swizzle both-sides (verified: 0 bank conflicts). Raw asm ds_read
// (keeps compiler from vmcnt-ordering vs in-flight global_load_lds) but with
// COUNTED lgkmcnt ladders so MFMA starts while later reads are in flight.
// 2 s_barrier per K-tile; counted vmcnt (never 0 in steady state).
template <int KD, int ND, int BM, int MAXT, bool GATHER, bool RELU>
__global__ __launch_bounds__(512, 2) void moe_gemm8(
    const uint16_t* __restrict__ A, const int* __restrict__ pair_tok,
    const uint16_t* __restrict__ Bw, const float* __restrict__ bias,
    uint16_t* __restrict__ C, const TileDesc* __restrict__ desc,
    const int* __restrict__ nt_ptr) {
  constexpr int NBC   = ND / 256;
  constexpr int NT    = KD / 64;
  constexpr int MR    = BM / 32;        // acc fragment rows per wave
  constexpr int ABYT  = BM * 128;       // A slot bytes
  constexpr int AREL  = 2 * BM * 64;    // B region start (elements)
  constexpr int SM    = MAXT / 8;       // mt-tiles per XCD
  constexpr int LPT   = BM / 64 + 4;    // gload_lds per thread per K-tile

  extern __shared__ char smem[];
  uint16_t* lds = (uint16_t*)smem;
  int* rowA = (int*)(smem + AREL * 2 + 65536);

  // XCD x owns mt in [x*SM,(x+1)*SM) for ALL nb; mt fastest within.
  int orig = blockIdx.x;
  int x = orig & 7, local = orig >> 3;
  int nb = local / SM;
  int mtl = x * SM + local % SM;
  if (mtl >= *nt_ptr) return;
  TileDesc d = desc[mtl];

  int tid = threadIdx.x, lane = tid & 63, wave = tid >> 6;
  int wm = wave >> 2, wn = wave & 3;

  if constexpr (GATHER) {
    if (tid < BM) rowA[tid] = (tid < d.rows) ? pair_tok[d.start + tid] : 0;
    __syncthreads();
  }

  int wl8 = wave * 8 + (lane >> 3);
  int colel = (((lane & 7) ^ (lane >> 3)) << 3);   // pre-swizzled source slot
  const uint16_t* Asrc[BM / 64];
  const uint16_t* Bsrc[4];
#pragma unroll
  for (int i = 0; i < BM / 64; ++i) {
    int r = i * 64 + wl8;
    int gr;
    if constexpr (GATHER) gr = rowA[r]; else gr = d.start + r;
    Asrc[i] = A + (size_t)gr * KD + colel;
  }
#pragma unroll
  for (int j = 0; j < 4; ++j)
    Bsrc[j] = Bw + ((size_t)d.e * ND + nb * 256 + j * 64 + wl8) * KD + colel;

  auto stage = [&](int slot, int kt) {
    int ko = kt * 64;
#pragma unroll
    for (int i = 0; i < BM / 64; ++i)
      gload_lds16(Asrc[i] + ko, &lds[slot * (BM * 64) + i * 4096 + wave * 512]);
#pragma unroll
    for (int j = 0; j < 4; ++j)
      gload_lds16(Bsrc[j] + ko, &lds[AREL + slot * 16384 + j * 4096 + wave * 512]);
  };

  uint32_t ldsu = (uint32_t)(uintptr_t)(AS3 char*)smem;
  int rd0 = (lane & 15) * 64 + ((((lane >> 4)) ^ (lane & 7)) << 3);
  int rd1 = (lane & 15) * 64 + ((((lane >> 4) | 4) ^ (lane & 7)) << 3);
  uint32_t aA0 = ldsu + (uint32_t)(wm * (BM * 32) + rd0) * 2;
  uint32_t aA1 = ldsu + (uint32_t)(wm * (BM * 32) + rd1) * 2;
  uint32_t aB0 = ldsu + (uint32_t)(AREL + wn * 4096 + rd0) * 2;
  uint32_t aB1 = ldsu + (uint32_t)(AREL + wn * 4096 + rd1) * 2;

  f32x4 acc[MR][4];
#pragma unroll
  for (int i = 0; i < MR; ++i)
#pragma unroll
    for (int j = 0; j < 4; ++j) acc[i][j] = (f32x4){0.f, 0.f, 0.f, 0.f};

  short8x aq[4][2], bA[2][2], bB[2][2];
  auto MM = [&](f32x4& c, const short8x& a0, const short8x& b0,
                const short8x& a1, const short8x& b1) {
    c = __builtin_amdgcn_mfma_f32_16x16x32_bf16(a0, b0, c, 0, 0, 0);
    c = __builtin_amdgcn_mfma_f32_16x16x32_bf16(a1, b1, c, 0, 0, 0);
  };

  stage(0, 0);
  stage(1, 1);
  if constexpr (BM == 256) asm volatile("s_waitcnt vmcnt(8)" ::: "memory");
  else                     asm volatile("s_waitcnt vmcnt(6)" ::: "memory");
  SBAR();

  for (int kt = 0; kt < NT; ++kt) {
    int slot = kt & 1;
    uint32_t saA = (uint32_t)slot * ABYT;
    uint32_t saB = (uint32_t)slot * 32768u;
    bool more = (kt + 2 < NT);

    // ---- Phase 1: issue B01 then A[0..3]; ladder 6/4/2/0; MFMA n0/1 ----
#pragma unroll
    for (int fn = 0; fn < 2; ++fn) {
      bA[fn][0] = ds128(aB0 + saB + fn * 2048);
      bA[fn][1] = ds128(aB1 + saB + fn * 2048);
    }
#pragma unroll
    for (int fm = 0; fm < 4; ++fm) {
      aq[fm][0] = ds128(aA0 + saA + fm * 2048);
      aq[fm][1] = ds128(aA1 + saA + fm * 2048);
    }
    __builtin_amdgcn_s_setprio(1);
    LGKM_SB(6);
    MM(acc[0][0], aq[0][0], bA[0][0], aq[0][1], bA[0][1]);
    MM(acc[0][1], aq[0][0], bA[1][0], aq[0][1], bA[1][1]);
    LGKM_SB(4);
    MM(acc[1][0], aq[1][0], bA[0][0], aq[1][1], bA[0][1]);
    MM(acc[1][1], aq[1][0], bA[1][0], aq[1][1], bA[1][1]);
    LGKM_SB(2);
    MM(acc[2][0], aq[2][0], bA[0][0], aq[2][1], bA[0][1]);
    MM(acc[2][1], aq[2][0], bA[1][0], aq[2][1], bA[1][1]);
    LGKM_SB(0);
    MM(acc[3][0], aq[3][0], bA[0][0], aq[3][1], bA[0][1]);
    MM(acc[3][1], aq[3][0], bA[1][0], aq[3][1], bA[1][1]);
    __builtin_amdgcn_s_setprio(0);

    // ---- Phase 2: issue B23; ladder 2/0; MFMA n2/3 (m-half0) ----
#pragma unroll
    for (int fn = 0; fn < 2; ++fn) {
      bB[fn][0] = ds128(aB0 + saB + (fn + 2) * 2048);
      bB[fn][1] = ds128(aB1 + saB + (fn + 2) * 2048);
    }
    __builtin_amdgcn_s_setprio(1);
    LGKM_SB(2);
#pragma unroll
    for (int fm = 0; fm < 4; ++fm)
      MM(acc[fm][2], aq[fm][0], bB[0][0], aq[fm][1], bB[0][1]);
    LGKM_SB(0);
    if constexpr (BM == 256) {
#pragma unroll
      for (int fm = 0; fm < 4; ++fm)
        MM(acc[fm][3], aq[fm][0], bB[1][0], aq[fm][1], bB[1][1]);
      __builtin_amdgcn_s_setprio(0);

      // ---- Phase 3: issue A[4..7]; ladder 6/4/2/0; MFMA (m-half1, n2/3) ----
#pragma unroll
      for (int fm = 0; fm < 4; ++fm) {
        aq[fm][0] = ds128(aA0 + saA + 8192 + fm * 2048);
        aq[fm][1] = ds128(aA1 + saA + 8192 + fm * 2048);
      }
      __builtin_amdgcn_s_setprio(1);
      LGKM_SB(6);
      MM(acc[4][2], aq[0][0], bB[0][0], aq[0][1], bB[0][1]);
      MM(acc[4][3], aq[0][0], bB[1][0], aq[0][1], bB[1][1]);
      LGKM_SB(4);
      MM(acc[5][2], aq[1][0], bB[0][0], aq[1][1], bB[0][1]);
      MM(acc[5][3], aq[1][0], bB[1][0], aq[1][1], bB[1][1]);
      LGKM_SB(2);
      MM(acc[6][2], aq[2][0], bB[0][0], aq[2][1], bB[0][1]);
      MM(acc[6][3], aq[2][0], bB[1][0], aq[2][1], bB[1][1]);
      LGKM_SB(0);
      MM(acc[7][2], aq[3][0], bB[0][0], aq[3][1], bB[0][1]);
      MM(acc[7][3], aq[3][0], bB[1][0], aq[3][1], bB[1][1]);
      __builtin_amdgcn_s_setprio(0);
      SBAR();   // all waves' reads of this slot complete -> safe to overwrite

      // ---- Phase 4: stage kt+2; MFMA (m-half1, n0/1); counted vmcnt ----
      if (more) stage(slot, kt + 2);
      __builtin_amdgcn_s_setprio(1);
#pragma unroll
      for (int fm = 0; fm < 4; ++fm) {
        MM(acc[fm + 4][0], aq[fm][0], bA[0][0], aq[fm][1], bA[0][1]);
        MM(acc[fm + 4][1], aq[fm][0], bA[1][0], aq[fm][1], bA[1][1]);
      }
      __builtin_amdgcn_s_setprio(0);
      if (more) asm volatile("s_waitcnt vmcnt(8)" ::: "memory");
      else      asm volatile("s_waitcnt vmcnt(0)" ::: "memory");
      SBAR();
    } else {
      // BM==128: finish with n3; stage mid-phase after barrier
      __builtin_amdgcn_s_setprio(0);
      SBAR();   // all waves' reads of this slot complete
      if (more) stage(slot, kt + 2);
      __builtin_amdgcn_s_setprio(1);
#pragma unroll
      for (int fm = 0; fm < 4; ++fm)
        MM(acc[fm][3], aq[fm][0], bB[1][0], aq[fm][1], bB[1][1]);
      __builtin_amdgcn_s_setprio(0);
      if (more) asm volatile("s_waitcnt vmcnt(6)" ::: "memory");
      else      asm volatile("s_waitcnt vmcnt(0)" ::: "memory");
      SBAR();
    }
  }

  // ---- epilogue ----
  int rq = (lane >> 4) * 4, cl = lane & 15;
  float bv[4];
#pragma unroll
  for (int fn = 0; fn < 4; ++fn)
    bv[fn] = bias[d.e * ND + nb * 256 + wn * 64 + fn * 16 + cl];
#pragma unroll
  for (int fm = 0; fm < MR; ++fm) {
    int rb = wm * (BM / 2) + fm * 16 + rq;
#pragma unroll
    for (int fn = 0; fn < 4; ++fn) {
      int col = nb * 256 + wn * 64 + fn * 16 + cl;
#pragma unroll
      for (int q = 0; q < 4; ++q) {
        int r = rb + q;
        if (r < d.rows) {
          float v = acc[fm][fn][q] + bv[fn];
          if constexpr (RELU) v = fmaxf(v, 0.f);
          C[(size_t)(d.start + r) * ND + col] = f2bf(v);
        }
      }
    }
  }
}

// ---------------- combine ----------------
__global__ __launch_bounds__(256) void combine_kernel(
    const uint16_t* __restrict__ po, const int* __restrict__ tok_pos,
    const float* __restrict__ topk_w, float* __restrict__ out) {
  int t = blockIdx.x;
  int c = threadIdx.x * 4;
  int p0 = tok_pos[t * 2], p1 = tok_pos[t * 2 + 1];
  float w0 = topk_w[t * 2], w1 = topk_w[t * 2 + 1];
  ushort4 a = *(const ushort4*)&po[(size_t)p0 * HD + c];
  ushort4 b = *(const ushort4*)&po[(size_t)p1 * HD + c];
  float4 o;
  o.x = w0 * bf2f(a.x) + w1 * bf2f(b.x);
  o.y = w0 * bf2f(a.y) + w1 * bf2f(b.y);
  o.z = w0 * bf2f(a.z) + w1 * bf2f(b.z);
  o.w = w0 * bf2f(a.w) + w1 * bf2f(b.w);
  *(float4*)&out[(size_t)t * HD + c] = o;
}

extern "C" void kernel_launch(void* const* d_in, const int* in_sizes, int n_in,
                              void* d_out, int out_size, void* d_ws, size_t ws_size,
                              hipStream_t stream) {
  const float* x      = (const float*)d_in[0];
  const float* gate_w = (const float*)d_in[1];
  const float* w1     = (const float*)d_in[2];
  const float* b1     = (const float*)d_in[3];
  const float* w2     = (const float*)d_in[4];
  const float* b2     = (const float*)d_in[5];
  float* out = (float*)d_out;
  (void)in_sizes; (void)n_in; (void)out_size; (void)ws_size;

  char* w = (char*)d_ws;
  size_t off = 0;
  auto alloc = [&](size_t bytes) -> void* {
    void* p = w + off;
    off = (off + bytes + 255) & ~(size_t)255;
    return p;
  };
  int*      meta      = (int*)alloc(256);
  int*      fill      = meta;
  int*      offsets   = (int*)alloc(256);
  int*      ntiles256 = offsets + 8;
  int*      ntiles128 = offsets + 9;
  TileDesc* desc256   = (TileDesc*)alloc(sizeof(TileDesc) * 64);
  TileDesc* desc128   = (TileDesc*)alloc(sizeof(TileDesc) * 128);
  int*      topk_idx  = (int*)alloc(sizeof(int) * P);
  float*    topk_w    = (float*)alloc(sizeof(float) * P);
  int*      tok_pos   = (int*)alloc(sizeof(int) * P);
  int*      pair_tok  = (int*)alloc(sizeof(int) * PPAD);
  float*    psums     = (float*)alloc(sizeof(float) * RNB * NE);
  int*      pcounts   = (int*)alloc(sizeof(int) * RNB * NE);
  uint16_t* xb        = (uint16_t*)alloc((size_t)T * HD * 2);
  uint16_t* w1t       = (uint16_t*)alloc((size_t)NE * FD * HD * 2);
  uint16_t* w2t       = (uint16_t*)alloc((size_t)NE * HD * FD * 2);
  uint16_t* hidden    = (uint16_t*)alloc((size_t)PPAD * FD * 2);
  uint16_t* pout      = (uint16_t*)alloc((size_t)PPAD * HD * 2);

  hipMemsetAsync(meta, 0, 256, stream);
  cvt_x_kernel<<<(T * HD) / 1024, 256, 0, stream>>>(x, xb);
  transpose_cvt_kernel<<<dim3(FD / 64, HD / 64, NE), 256, 0, stream>>>(w1, w1t, HD, FD);
  transpose_cvt_kernel<<<dim3(HD / 64, FD / 64, NE), 256, 0, stream>>>(w2, w2t, FD, HD);
  router_kernel<<<RNB, 256, 0, stream>>>(x, gate_w, topk_idx, topk_w, psums, pcounts);
  finalize_kernel<<<1, 64, 0, stream>>>(pcounts, psums, offsets, desc256, desc128,
                                        ntiles256, ntiles128, out + (size_t)T * HD);
  scatter_kernel<<<T / 256, 256, 0, stream>>>(topk_idx, offsets, fill, pair_tok, tok_pos);
  // fc1: 256x256, gather+relu. LDS: 128K + 1K rowA
  moe_gemm8<HD, FD, 256, MAXT256, true, true>
      <<<(FD / 256) * MAXT256, 512, 132096, stream>>>(
      xb, pair_tok, w1t, b1, hidden, desc256, ntiles256);
  // fc2: 128x256. LDS: 96K
  moe_gemm8<FD, HD, 128, MAXT128, false, false>
      <<<(HD / 256) * MAXT128, 512, 98304, stream>>>(
      hidden, nullptr, w2t, b2, pout, desc128, ntiles128);
  combine_kernel<<<T, 256, 0, stream>>>(pout, tok_pos, topk_w, out);
}

// Round 7
// 406.592 us; speedup vs baseline: 1.0437x; 1.0135x over previous
//
#include <hip/hip_runtime.h>
#include <hip/hip_bf16.h>
#include <cstdint>

#define AS1 __attribute__((address_space(1)))
#define AS3 __attribute__((address_space(3)))
#define SBAR() asm volatile("s_barrier" ::: "memory")
#define LGKM0() asm volatile("s_waitcnt lgkmcnt(0)" ::: "memory")

typedef __attribute__((ext_vector_type(8))) short short8x;   // 8 bf16 (4 VGPRs)
typedef __attribute__((ext_vector_type(4))) float f32x4;     // MFMA C/D

static constexpr int T    = 4096;
static constexpr int HD   = 1024;
static constexpr int FD   = 4096;
static constexpr int NE   = 8;
static constexpr int P    = T * 2;
static constexpr int PPAD = P + 256;
static constexpr int MAXT256 = P / 256 + NE;  // 40 (256-row tiles), % 8 == 0
static constexpr int RTB  = 16;
static constexpr int RNB  = T / RTB;

struct TileDesc { int e; int start; int rows; int pad; };

__device__ __forceinline__ uint16_t f2bf(float f) {
  uint32_t u = __builtin_bit_cast(uint32_t, f);
  u += 0x7FFFu + ((u >> 16) & 1u);
  return (uint16_t)(u >> 16);
}
__device__ __forceinline__ float bf2f(uint16_t b) {
  uint32_t u = ((uint32_t)b) << 16;
  return __builtin_bit_cast(float, u);
}
__device__ __forceinline__ void gload_lds16(const void* g, void* l) {
  __builtin_amdgcn_global_load_lds((const AS1 uint32_t*)g, (AS3 uint32_t*)l, 16, 0, 0);
}

// ---------------- x fp32 -> bf16 ----------------
__global__ __launch_bounds__(256) void cvt_x_kernel(const float* __restrict__ x,
                                                    uint16_t* __restrict__ xb) {
  size_t i = ((size_t)blockIdx.x * 256 + threadIdx.x) * 4;
  float4 v = *(const float4*)&x[i];
  ushort4 o;
  o.x = f2bf(v.x); o.y = f2bf(v.y); o.z = f2bf(v.z); o.w = f2bf(v.w);
  *(ushort4*)&xb[i] = o;
}

// ------------- transpose + cvt: in [z][R][C] f32 -> out [z][C][R] bf16 -------------
__global__ __launch_bounds__(256) void transpose_cvt_kernel(
    const float* __restrict__ in, uint16_t* __restrict__ out, int R, int C) {
  __shared__ float tile[64][65];
  int z = blockIdx.z;
  const float* inp = in + (size_t)z * R * C;
  uint16_t* outp = out + (size_t)z * R * C;
  int r0 = blockIdx.y * 64, c0 = blockIdx.x * 64;
  int tid = threadIdx.x;
  int lr = tid >> 4;
  int lc4 = (tid & 15) * 4;
#pragma unroll
  for (int p = 0; p < 4; ++p) {
    float4 v = *(const float4*)&inp[(size_t)(r0 + lr + p * 16) * C + c0 + lc4];
    tile[lr + p * 16][lc4 + 0] = v.x;
    tile[lr + p * 16][lc4 + 1] = v.y;
    tile[lr + p * 16][lc4 + 2] = v.z;
    tile[lr + p * 16][lc4 + 3] = v.w;
  }
  __syncthreads();
#pragma unroll
  for (int p = 0; p < 4; ++p) {
    int c = lr + p * 16;
    ushort4 o;
    o.x = f2bf(tile[lc4 + 0][c]);
    o.y = f2bf(tile[lc4 + 1][c]);
    o.z = f2bf(tile[lc4 + 2][c]);
    o.w = f2bf(tile[lc4 + 3][c]);
    *(ushort4*)&outp[(size_t)(c0 + c) * R + r0 + lc4] = o;
  }
}

// ---------------- router ----------------
__global__ __launch_bounds__(256) void router_kernel(
    const float* __restrict__ x, const float* __restrict__ gate_w,
    int* __restrict__ topk_idx, float* __restrict__ topk_w,
    float* __restrict__ part_sums, int* __restrict__ part_counts) {
  __shared__ float g[NE * HD];
  __shared__ float ls[NE];
  __shared__ int   lc[NE];
  int tid = threadIdx.x;
  for (int i = tid; i < NE * HD; i += 256)
    g[(i & 7) * HD + (i >> 3)] = gate_w[i];
  if (tid < NE) { ls[tid] = 0.f; lc[tid] = 0; }
  __syncthreads();
  int wave = tid >> 6, lane = tid & 63;
  float psum[NE];
#pragma unroll
  for (int e = 0; e < NE; ++e) psum[e] = 0.f;

  for (int tt = 0; tt < RTB / 4; ++tt) {
    int t = blockIdx.x * RTB + wave * (RTB / 4) + tt;
    const float* xr = x + (size_t)t * HD;
    float acc[NE];
#pragma unroll
    for (int e = 0; e < NE; ++e) acc[e] = 0.f;
    for (int i = 0; i < HD / 64; ++i) {
      float xv = xr[lane + i * 64];
#pragma unroll
      for (int e = 0; e < NE; ++e) acc[e] += xv * g[e * HD + lane + i * 64];
    }
#pragma unroll
    for (int off = 32; off > 0; off >>= 1)
#pragma unroll
      for (int e = 0; e < NE; ++e) acc[e] += __shfl_down(acc[e], off);
    if (lane == 0) {
      float m = acc[0];
#pragma unroll
      for (int e = 1; e < NE; ++e) m = fmaxf(m, acc[e]);
      float p[NE], s = 0.f;
#pragma unroll
      for (int e = 0; e < NE; ++e) { p[e] = expf(acc[e] - m); s += p[e]; }
      float inv = 1.f / s;
#pragma unroll
      for (int e = 0; e < NE; ++e) { p[e] *= inv; psum[e] += p[e]; }
      int i0 = 0;
#pragma unroll
      for (int e = 1; e < NE; ++e) if (p[e] > p[i0]) i0 = e;
      int i1 = (i0 == 0) ? 1 : 0;
#pragma unroll
      for (int e = 0; e < NE; ++e) if (e != i0 && e != i1 && p[e] > p[i1]) i1 = e;
      float wsum = p[i0] + p[i1];
      topk_idx[t * 2] = i0; topk_idx[t * 2 + 1] = i1;
      topk_w[t * 2] = p[i0] / wsum; topk_w[t * 2 + 1] = p[i1] / wsum;
      atomicAdd(&lc[i0], 1); atomicAdd(&lc[i1], 1);
    }
  }
  if (lane == 0)
#pragma unroll
    for (int e = 0; e < NE; ++e) atomicAdd(&ls[e], psum[e]);
  __syncthreads();
  if (tid < NE) {
    part_sums[blockIdx.x * NE + tid]   = ls[tid];
    part_counts[blockIdx.x * NE + tid] = lc[tid];
  }
}

// ---------------- finalize ----------------
__global__ __launch_bounds__(64) void finalize_kernel(
    const int* __restrict__ part_counts, const float* __restrict__ part_sums,
    int* __restrict__ offsets, TileDesc* __restrict__ desc256,
    int* __restrict__ ntiles256, float* __restrict__ aux_out) {
  __shared__ int   csh[NE];
  __shared__ float ssh[NE];
  int tid = threadIdx.x;
  if (tid < NE) {
    int c = 0; float s = 0.f;
    for (int b = 0; b < RNB; ++b) {
      c += part_counts[b * NE + tid];
      s += part_sums[b * NE + tid];
    }
    csh[tid] = c; ssh[tid] = s;
  }
  __syncthreads();
  if (tid == 0) {
    int off = 0, n2 = 0;
    for (int e = 0; e < NE; ++e) {
      offsets[e] = off;
      int c = csh[e];
      for (int i = 0; i < c; i += 256) {
        int rows = c - i; if (rows > 256) rows = 256;
        desc256[n2].e = e; desc256[n2].start = off + i; desc256[n2].rows = rows;
        desc256[n2].pad = 0; n2++;
      }
      off += c;
    }
    *ntiles256 = n2;
    float aux = 0.f;
    for (int e = 0; e < NE; ++e) {
      float mean = ssh[e] / (float)T;
      aux += mean * mean;
    }
    *aux_out = (float)NE * aux;
  }
}

// ---------------- scatter ----------------
__global__ __launch_bounds__(256) void scatter_kernel(
    const int* __restrict__ topk_idx, const int* __restrict__ offsets,
    int* __restrict__ fill, int* __restrict__ pair_tok, int* __restrict__ tok_pos) {
  int t = blockIdx.x * 256 + threadIdx.x;
  int lane = threadIdx.x & 63;
  unsigned long long below = (lane == 63) ? ~0ull >> 1
                                          : ((1ull << (lane + 1)) - 1) >> 1;
#pragma unroll
  for (int k = 0; k < 2; ++k) {
    int e = topk_idx[t * 2 + k];
    int pos = 0;
    for (int ex = 0; ex < NE; ++ex) {
      unsigned long long m = __ballot(e == ex);
      if (e == ex) {
        int leader = __ffsll((long long)m) - 1;
        int cnt = __popcll(m);
        int base = 0;
        if (lane == leader) base = atomicAdd(&fill[ex], cnt);
        base = __shfl(base, leader);
        pos = base + __popcll(m & below);
      }
    }
    int pp = offsets[e] + pos;
    pair_tok[pp] = t;
    tok_pos[t * 2 + k] = pp;
  }
}

// ============ 256xBN 8-phase MFMA GEMM — faithful m201 template port ============
// C[rows,ND] = A[rows,KD] * Bw[e][ND,KD]^T (+bias, opt relu)
// BM=256, BK=64, 8 waves (2M x 4N), per-wave 128x(BN/4). 2-slot dbuf.
// Per phase: {ds-read one quadrant's frags | stage 2 granules (8KB each) |
//  SBAR | lgkmcnt(0) | setprio(1) 16(or 8) MFMA setprio(0) | SBAR}.
// vmcnt counted ONCE per K-tile at phase 4 (6 for BN=256, 4 for BN=128).
// Granule stream is consumption-safe: a region is overwritten only in a phase
// after the one that read it. Swizzle: 3-bit XOR both-sides (verified 0 confl).
template <int KD, int ND, int BN, bool GATHER, bool RELU>
__global__ __launch_bounds__(512, 2) void moe_gemm8(
    const uint16_t* __restrict__ A, const int* __restrict__ pair_tok,
    const uint16_t* __restrict__ Bw, const float* __restrict__ bias,
    uint16_t* __restrict__ C, const TileDesc* __restrict__ desc,
    const int* __restrict__ nt_ptr) {
  constexpr int NBC = ND / BN;
  constexpr int NT  = KD / 64;
  constexpr int ASL = 16384;        // A slot elements (256x64)
  constexpr int BSL = BN * 64;      // B slot elements
  constexpr int BOFF = 2 * ASL;     // B region base (elements)
  constexpr int WN  = BN / 4;       // cols per wave
  constexpr int FN  = BN / 64;      // n-frags per wave
  constexpr int FH  = FN / 2;       // n-frags per quadrant
  constexpr int NGB = BN / 64;      // B col-groups (granules)
  constexpr int G   = 4 + NGB;      // granules per K-tile (8 or 6)
  constexpr int GRIDT = NBC * MAXT256;
  constexpr int SMX = MAXT256 / 8;  // 5

  extern __shared__ char smem[];
  uint16_t* lds = (uint16_t*)smem;
  int* rowA = (int*)(smem + (2 * ASL + 2 * BSL) * 2);

  int orig = blockIdx.x;
  int xcd = orig & 7, local = orig >> 3;        // XCD-bijective (GRIDT % 8 == 0)
  int nb = local / SMX;
  int mtl = xcd * SMX + local % SMX;
  if (mtl >= *nt_ptr) return;
  TileDesc d = desc[mtl];

  int tid = threadIdx.x, lane = tid & 63, wave = tid >> 6;
  int wm = wave >> 2, wn = wave & 3;
  int l15 = lane & 15, l7 = lane & 7, lk = lane >> 4;

  if constexpr (GATHER) {
    if (tid < 256) rowA[tid] = (tid < d.rows) ? pair_tok[d.start + tid] : 0;
    __syncthreads();
  }

  // ---- staging source pointers (pre-swizzled: source 16B-slot = (lane&7)^(row&7)) ----
  int wl8 = wave * 8 + (lane >> 3);
  int colel = (((lane & 7) ^ (lane >> 3)) << 3);
  const uint16_t* Asrc[4];
  const uint16_t* Bsrc[NGB];
#pragma unroll
  for (int i = 0; i < 4; ++i) {
    int r = i * 64 + wl8;
    int gr;
    if constexpr (GATHER) gr = rowA[r]; else gr = d.start + r;
    Asrc[i] = A + (size_t)gr * KD + colel;
  }
#pragma unroll
  for (int j = 0; j < NGB; ++j)
    Bsrc[j] = Bw + ((size_t)d.e * ND + nb * BN + j * 64 + wl8) * KD + colel;

  auto stageA = [&](int tile, int i) {
    gload_lds16(Asrc[i] + tile * 64, lds + (tile & 1) * ASL + i * 4096 + wave * 512);
  };
  auto stageB = [&](int tile, int j) {
    gload_lds16(Bsrc[j] + tile * 64, lds + BOFF + (tile & 1) * BSL + j * 4096 + wave * 512);
  };
  // granule stream (consumption-safe order)
  auto stage_g = [&](int tile, int g) {
    if (tile >= NT) return;
    if constexpr (BN == 256) {
      switch (g) {
        case 0: stageA(tile, 0); break;  // A-rg0  (consumed P1)
        case 1: stageA(tile, 2); break;  // A-rg2  (consumed P1)
        case 2: stageB(tile, 0); break;  // B-cg0  (consumed by P2)
        case 3: stageB(tile, 1); break;
        case 4: stageB(tile, 2); break;
        case 5: stageB(tile, 3); break;
        case 6: stageA(tile, 1); break;  // A-rg1  (consumed P3)
        case 7: stageA(tile, 3); break;  // A-rg3  (consumed P3)
      }
    } else {
      switch (g) {
        case 0: stageA(tile, 0); break;
        case 1: stageA(tile, 2); break;
        case 2: stageB(tile, 0); break;
        case 3: stageB(tile, 1); break;
        case 4: stageA(tile, 1); break;
        case 5: stageA(tile, 3); break;
      }
    }
  };

  // ---- fragment read bases (element offsets, swizzled) ----
  int aBase = (wm * 128 + l15) * 64;
  int bBase = (wn * WN + l15) * 64;
  int sw0 = ((lk) ^ l7) * 8;
  int sw1 = ((4 + lk) ^ l7) * 8;
  auto LD = [&](int o) { return *(const short8x*)(lds + o); };

  f32x4 acc[8][FN];
#pragma unroll
  for (int i = 0; i < 8; ++i)
#pragma unroll
    for (int j = 0; j < FN; ++j) acc[i][j] = (f32x4){0.f, 0.f, 0.f, 0.f};

  short8x aq[4][2], bq0[FH][2], bq1[FH][2];
  auto MM2 = [&](f32x4& c, const short8x (&a)[2], const short8x (&b)[2]) {
    c = __builtin_amdgcn_mfma_f32_16x16x32_bf16(a[0], b[0], c, 0, 0, 0);
    c = __builtin_amdgcn_mfma_f32_16x16x32_bf16(a[1], b[1], c, 0, 0, 0);
  };

  // ---- prologue: tile0 full (G), tile1 minus last 2 -> vmcnt(G-2) ----
#pragma unroll
  for (int g = 0; g < G; ++g) stage_g(0, g);
#pragma unroll
  for (int g = 0; g < G - 2; ++g) stage_g(1, g);
  if constexpr (BN == 256) asm volatile("s_waitcnt vmcnt(6)" ::: "memory");
  else                     asm volatile("s_waitcnt vmcnt(4)" ::: "memory");
  SBAR();

  for (int kt = 0; kt < NT; ++kt) {
    const int sA = (kt & 1) * ASL;
    const int sB = BOFF + (kt & 1) * BSL;

    // ---- Phase 1: quadrant (mh0, n-first-half) ----
#pragma unroll
    for (int fm = 0; fm < 4; ++fm) {
      aq[fm][0] = LD(sA + aBase + fm * 1024 + sw0);
      aq[fm][1] = LD(sA + aBase + fm * 1024 + sw1);
    }
#pragma unroll
    for (int fn = 0; fn < FH; ++fn) {
      bq0[fn][0] = LD(sB + bBase + fn * 1024 + sw0);
      bq0[fn][1] = LD(sB + bBase + fn * 1024 + sw1);
    }
    stage_g(kt + 1, G - 2); stage_g(kt + 1, G - 1);
    SBAR();
    LGKM0();
    __builtin_amdgcn_s_setprio(1);
#pragma unroll
    for (int fm = 0; fm < 4; ++fm)
#pragma unroll
      for (int fn = 0; fn < FH; ++fn) MM2(acc[fm][fn], aq[fm], bq0[fn]);
    __builtin_amdgcn_s_setprio(0);
    SBAR();

    // ---- Phase 2: quadrant (mh0, n-second-half) ----
#pragma unroll
    for (int fn = 0; fn < FH; ++fn) {
      bq1[fn][0] = LD(sB + bBase + (FH + fn) * 1024 + sw0);
      bq1[fn][1] = LD(sB + bBase + (FH + fn) * 1024 + sw1);
    }
    stage_g(kt + 2, 0); stage_g(kt + 2, 1);
    SBAR();
    LGKM0();
    __builtin_amdgcn_s_setprio(1);
#pragma unroll
    for (int fm = 0; fm < 4; ++fm)
#pragma unroll
      for (int fn = 0; fn < FH; ++fn) MM2(acc[fm][FH + fn], aq[fm], bq1[fn]);
    __builtin_amdgcn_s_setprio(0);
    SBAR();

    // ---- Phase 3: quadrant (mh1, n-second-half) ----
#pragma unroll
    for (int fm = 0; fm < 4; ++fm) {
      aq[fm][0] = LD(sA + aBase + 4096 + fm * 1024 + sw0);
      aq[fm][1] = LD(sA + aBase + 4096 + fm * 1024 + sw1);
    }
    stage_g(kt + 2, 2); stage_g(kt + 2, 3);
    SBAR();
    LGKM0();
    __builtin_amdgcn_s_setprio(1);
#pragma unroll
    for (int fm = 0; fm < 4; ++fm)
#pragma unroll
      for (int fn = 0; fn < FH; ++fn) MM2(acc[4 + fm][FH + fn], aq[fm], bq1[fn]);
    __builtin_amdgcn_s_setprio(0);
    SBAR();

    // ---- Phase 4: quadrant (mh1, n-first-half); stage; counted vmcnt ----
    if constexpr (BN == 256) { stage_g(kt + 2, 4); stage_g(kt + 2, 5); }
    __builtin_amdgcn_s_setprio(1);
#pragma unroll
    for (int fm = 0; fm < 4; ++fm)
#pragma unroll
      for (int fn = 0; fn < FH; ++fn) MM2(acc[4 + fm][fn], aq[fm], bq0[fn]);
    __builtin_amdgcn_s_setprio(0);
    if (kt + 2 < NT) {
      if constexpr (BN == 256) asm volatile("s_waitcnt vmcnt(6)" ::: "memory");
      else                     asm volatile("s_waitcnt vmcnt(4)" ::: "memory");
    } else {
      asm volatile("s_waitcnt vmcnt(0)" ::: "memory");
    }
    SBAR();
  }

  // ---- epilogue ----
  int rq = lk * 4, cl = l15;
  float bv[FN];
#pragma unroll
  for (int fn = 0; fn < FN; ++fn)
    bv[fn] = bias[d.e * ND + nb * BN + wn * WN + fn * 16 + cl];
#pragma unroll
  for (int fm = 0; fm < 8; ++fm) {
    int rb = wm * 128 + (fm & 3) * 16 + (fm >> 2) * 64 + rq;
#pragma unroll
    for (int fn = 0; fn < FN; ++fn) {
      int col = nb * BN + wn * WN + fn * 16 + cl;
#pragma unroll
      for (int q = 0; q < 4; ++q) {
        int r = rb + q;
        if (r < d.rows) {
          float v = acc[fm][fn][q] + bv[fn];
          if constexpr (RELU) v = fmaxf(v, 0.f);
          C[(size_t)(d.start + r) * ND + col] = f2bf(v);
        }
      }
    }
  }
}

// ---------------- combine ----------------
__global__ __launch_bounds__(256) void combine_kernel(
    const uint16_t* __restrict__ po, const int* __restrict__ tok_pos,
    const float* __restrict__ topk_w, float* __restrict__ out) {
  int t = blockIdx.x;
  int c = threadIdx.x * 4;
  int p0 = tok_pos[t * 2], p1 = tok_pos[t * 2 + 1];
  float w0 = topk_w[t * 2], w1 = topk_w[t * 2 + 1];
  ushort4 a = *(const ushort4*)&po[(size_t)p0 * HD + c];
  ushort4 b = *(const ushort4*)&po[(size_t)p1 * HD + c];
  float4 o;
  o.x = w0 * bf2f(a.x) + w1 * bf2f(b.x);
  o.y = w0 * bf2f(a.y) + w1 * bf2f(b.y);
  o.z = w0 * bf2f(a.z) + w1 * bf2f(b.z);
  o.w = w0 * bf2f(a.w) + w1 * bf2f(b.w);
  *(float4*)&out[(size_t)t * HD + c] = o;
}

extern "C" void kernel_launch(void* const* d_in, const int* in_sizes, int n_in,
                              void* d_out, int out_size, void* d_ws, size_t ws_size,
                              hipStream_t stream) {
  const float* x      = (const float*)d_in[0];
  const float* gate_w = (const float*)d_in[1];
  const float* w1     = (const float*)d_in[2];
  const float* b1     = (const float*)d_in[3];
  const float* w2     = (const float*)d_in[4];
  const float* b2     = (const float*)d_in[5];
  float* out = (float*)d_out;
  (void)in_sizes; (void)n_in; (void)out_size; (void)ws_size;

  char* w = (char*)d_ws;
  size_t off = 0;
  auto alloc = [&](size_t bytes) -> void* {
    void* p = w + off;
    off = (off + bytes + 255) & ~(size_t)255;
    return p;
  };
  int*      meta      = (int*)alloc(256);
  int*      fill      = meta;
  int*      offsets   = (int*)alloc(256);
  int*      ntiles256 = offsets + 8;
  TileDesc* desc256   = (TileDesc*)alloc(sizeof(TileDesc) * 64);
  int*      topk_idx  = (int*)alloc(sizeof(int) * P);
  float*    topk_w    = (float*)alloc(sizeof(float) * P);
  int*      tok_pos   = (int*)alloc(sizeof(int) * P);
  int*      pair_tok  = (int*)alloc(sizeof(int) * PPAD);
  float*    psums     = (float*)alloc(sizeof(float) * RNB * NE);
  int*      pcounts   = (int*)alloc(sizeof(int) * RNB * NE);
  uint16_t* xb        = (uint16_t*)alloc((size_t)T * HD * 2);
  uint16_t* w1t       = (uint16_t*)alloc((size_t)NE * FD * HD * 2);
  uint16_t* w2t       = (uint16_t*)alloc((size_t)NE * HD * FD * 2);
  uint16_t* hidden    = (uint16_t*)alloc((size_t)PPAD * FD * 2);
  uint16_t* pout      = (uint16_t*)alloc((size_t)PPAD * HD * 2);

  hipMemsetAsync(meta, 0, 256, stream);
  cvt_x_kernel<<<(T * HD) / 1024, 256, 0, stream>>>(x, xb);
  transpose_cvt_kernel<<<dim3(FD / 64, HD / 64, NE), 256, 0, stream>>>(w1, w1t, HD, FD);
  transpose_cvt_kernel<<<dim3(HD / 64, FD / 64, NE), 256, 0, stream>>>(w2, w2t, FD, HD);
  router_kernel<<<RNB, 256, 0, stream>>>(x, gate_w, topk_idx, topk_w, psums, pcounts);
  finalize_kernel<<<1, 64, 0, stream>>>(pcounts, psums, offsets, desc256, ntiles256,
                                        out + (size_t)T * HD);
  scatter_kernel<<<T / 256, 256, 0, stream>>>(topk_idx, offsets, fill, pair_tok, tok_pos);
  // fc1: 256x256 (LDS 128K + 1K rowA), grid 640
  moe_gemm8<HD, FD, 256, true, true>
      <<<(FD / 256) * MAXT256, 512, 132096, stream>>>(
      xb, pair_tok, w1t, b1, hidden, desc256, ntiles256);
  // fc2: 256x128 (LDS 96K), grid 320
  moe_gemm8<FD, HD, 128, false, false>
      <<<(HD / 128) * MAXT256, 512, 98304, stream>>>(
      hidden, nullptr, w2t, b2, pout, desc256, ntiles256);
  combine_kernel<<<T, 256, 0, stream>>>(pout, tok_pos, topk_w, out);
}

// Round 8
// 370.471 us; speedup vs baseline: 1.1454x; 1.0975x over previous
//
#include <hip/hip_runtime.h>
#include <hip/hip_bf16.h>
#include <cstdint>

#define AS1 __attribute__((address_space(1)))
#define AS3 __attribute__((address_space(3)))

typedef __attribute__((ext_vector_type(8))) short short8x;   // 8 bf16 (4 VGPRs)
typedef __attribute__((ext_vector_type(4))) float f32x4;     // MFMA C/D

static constexpr int T    = 4096;
static constexpr int HD   = 1024;
static constexpr int FD   = 4096;
static constexpr int NE   = 8;
static constexpr int P    = T * 2;
static constexpr int PPAD = P + 128;
static constexpr int MAXT = P / 128 + NE;   // 72 (128-row tiles), % 8 == 0
static constexpr int RTB  = 16;
static constexpr int RNB  = T / RTB;

struct TileDesc { int e; int start; int rows; int pad; };

__device__ __forceinline__ uint16_t f2bf(float f) {
  uint32_t u = __builtin_bit_cast(uint32_t, f);
  u += 0x7FFFu + ((u >> 16) & 1u);
  return (uint16_t)(u >> 16);
}
__device__ __forceinline__ float bf2f(uint16_t b) {
  uint32_t u = ((uint32_t)b) << 16;
  return __builtin_bit_cast(float, u);
}
__device__ __forceinline__ void gload_lds16(const void* g, void* l) {
  __builtin_amdgcn_global_load_lds((const AS1 uint32_t*)g, (AS3 uint32_t*)l, 16, 0, 0);
}

// ---------------- x fp32 -> bf16 ----------------
__global__ __launch_bounds__(256) void cvt_x_kernel(const float* __restrict__ x,
                                                    uint16_t* __restrict__ xb) {
  size_t i = ((size_t)blockIdx.x * 256 + threadIdx.x) * 4;
  float4 v = *(const float4*)&x[i];
  ushort4 o;
  o.x = f2bf(v.x); o.y = f2bf(v.y); o.z = f2bf(v.z); o.w = f2bf(v.w);
  *(ushort4*)&xb[i] = o;
}

// ------------- transpose + cvt: in [z][R][C] f32 -> out [z][C][R] bf16 -------------
__global__ __launch_bounds__(256) void transpose_cvt_kernel(
    const float* __restrict__ in, uint16_t* __restrict__ out, int R, int C) {
  __shared__ float tile[64][65];
  int z = blockIdx.z;
  const float* inp = in + (size_t)z * R * C;
  uint16_t* outp = out + (size_t)z * R * C;
  int r0 = blockIdx.y * 64, c0 = blockIdx.x * 64;
  int tid = threadIdx.x;
  int lr = tid >> 4;
  int lc4 = (tid & 15) * 4;
#pragma unroll
  for (int p = 0; p < 4; ++p) {
    float4 v = *(const float4*)&inp[(size_t)(r0 + lr + p * 16) * C + c0 + lc4];
    tile[lr + p * 16][lc4 + 0] = v.x;
    tile[lr + p * 16][lc4 + 1] = v.y;
    tile[lr + p * 16][lc4 + 2] = v.z;
    tile[lr + p * 16][lc4 + 3] = v.w;
  }
  __syncthreads();
#pragma unroll
  for (int p = 0; p < 4; ++p) {
    int c = lr + p * 16;
    ushort4 o;
    o.x = f2bf(tile[lc4 + 0][c]);
    o.y = f2bf(tile[lc4 + 1][c]);
    o.z = f2bf(tile[lc4 + 2][c]);
    o.w = f2bf(tile[lc4 + 3][c]);
    *(ushort4*)&outp[(size_t)(c0 + c) * R + r0 + lc4] = o;
  }
}

// ---------------- router ----------------
__global__ __launch_bounds__(256) void router_kernel(
    const float* __restrict__ x, const float* __restrict__ gate_w,
    int* __restrict__ topk_idx, float* __restrict__ topk_w,
    float* __restrict__ part_sums, int* __restrict__ part_counts) {
  __shared__ float g[NE * HD];
  __shared__ float ls[NE];
  __shared__ int   lc[NE];
  int tid = threadIdx.x;
  for (int i = tid; i < NE * HD; i += 256)
    g[(i & 7) * HD + (i >> 3)] = gate_w[i];
  if (tid < NE) { ls[tid] = 0.f; lc[tid] = 0; }
  __syncthreads();
  int wave = tid >> 6, lane = tid & 63;
  float psum[NE];
#pragma unroll
  for (int e = 0; e < NE; ++e) psum[e] = 0.f;

  for (int tt = 0; tt < RTB / 4; ++tt) {
    int t = blockIdx.x * RTB + wave * (RTB / 4) + tt;
    const float* xr = x + (size_t)t * HD;
    float acc[NE];
#pragma unroll
    for (int e = 0; e < NE; ++e) acc[e] = 0.f;
    for (int i = 0; i < HD / 64; ++i) {
      float xv = xr[lane + i * 64];
#pragma unroll
      for (int e = 0; e < NE; ++e) acc[e] += xv * g[e * HD + lane + i * 64];
    }
#pragma unroll
    for (int off = 32; off > 0; off >>= 1)
#pragma unroll
      for (int e = 0; e < NE; ++e) acc[e] += __shfl_down(acc[e], off);
    if (lane == 0) {
      float m = acc[0];
#pragma unroll
      for (int e = 1; e < NE; ++e) m = fmaxf(m, acc[e]);
      float p[NE], s = 0.f;
#pragma unroll
      for (int e = 0; e < NE; ++e) { p[e] = expf(acc[e] - m); s += p[e]; }
      float inv = 1.f / s;
#pragma unroll
      for (int e = 0; e < NE; ++e) { p[e] *= inv; psum[e] += p[e]; }
      int i0 = 0;
#pragma unroll
      for (int e = 1; e < NE; ++e) if (p[e] > p[i0]) i0 = e;
      int i1 = (i0 == 0) ? 1 : 0;
#pragma unroll
      for (int e = 0; e < NE; ++e) if (e != i0 && e != i1 && p[e] > p[i1]) i1 = e;
      float wsum = p[i0] + p[i1];
      topk_idx[t * 2] = i0; topk_idx[t * 2 + 1] = i1;
      topk_w[t * 2] = p[i0] / wsum; topk_w[t * 2 + 1] = p[i1] / wsum;
      atomicAdd(&lc[i0], 1); atomicAdd(&lc[i1], 1);
    }
  }
  if (lane == 0)
#pragma unroll
    for (int e = 0; e < NE; ++e) atomicAdd(&ls[e], psum[e]);
  __syncthreads();
  if (tid < NE) {
    part_sums[blockIdx.x * NE + tid]   = ls[tid];
    part_counts[blockIdx.x * NE + tid] = lc[tid];
  }
}

// ---------------- finalize ----------------
__global__ __launch_bounds__(64) void finalize_kernel(
    const int* __restrict__ part_counts, const float* __restrict__ part_sums,
    int* __restrict__ offsets, TileDesc* __restrict__ desc,
    int* __restrict__ ntiles, float* __restrict__ aux_out) {
  __shared__ int   csh[NE];
  __shared__ float ssh[NE];
  int tid = threadIdx.x;
  if (tid < NE) {
    int c = 0; float s = 0.f;
    for (int b = 0; b < RNB; ++b) {
      c += part_counts[b * NE + tid];
      s += part_sums[b * NE + tid];
    }
    csh[tid] = c; ssh[tid] = s;
  }
  __syncthreads();
  if (tid == 0) {
    int off = 0, nt = 0;
    for (int e = 0; e < NE; ++e) {
      offsets[e] = off;
      int c = csh[e];
      for (int i = 0; i < c; i += 128) {
        int rows = c - i; if (rows > 128) rows = 128;
        desc[nt].e = e; desc[nt].start = off + i; desc[nt].rows = rows; desc[nt].pad = 0;
        nt++;
      }
      off += c;
    }
    *ntiles = nt;
    float aux = 0.f;
    for (int e = 0; e < NE; ++e) {
      float mean = ssh[e] / (float)T;
      aux += mean * mean;
    }
    *aux_out = (float)NE * aux;
  }
}

// ---------------- scatter ----------------
__global__ __launch_bounds__(256) void scatter_kernel(
    const int* __restrict__ topk_idx, const int* __restrict__ offsets,
    int* __restrict__ fill, int* __restrict__ pair_tok, int* __restrict__ tok_pos) {
  int t = blockIdx.x * 256 + threadIdx.x;
  int lane = threadIdx.x & 63;
  unsigned long long below = (lane == 63) ? ~0ull >> 1
                                          : ((1ull << (lane + 1)) - 1) >> 1;
#pragma unroll
  for (int k = 0; k < 2; ++k) {
    int e = topk_idx[t * 2 + k];
    int pos = 0;
    for (int ex = 0; ex < NE; ++ex) {
      unsigned long long m = __ballot(e == ex);
      if (e == ex) {
        int leader = __ffsll((long long)m) - 1;
        int cnt = __popcll(m);
        int base = 0;
        if (lane == leader) base = atomicAdd(&fill[ex], cnt);
        base = __shfl(base, leader);
        pos = base + __popcll(m & below);
      }
    }
    int pp = offsets[e] + pos;
    pair_tok[pp] = t;
    tok_pos[t * 2 + k] = pp;
  }
}

// ---------------- MFMA GEMM: R2's proven m97-structure inner loop (verbatim) ----------------
// ONLY change vs R2: block->tile mapping (XCD-bijective + per-XCD mt-supertile with
// nb grouped NBG) for L2 locality. 4-5 blocks/CU (static 32.5KB LDS) -> TLP hides latency.
// C[rows,ND] = A[rows,KD] * Bw[e][ND,KD]^T (+bias, opt relu)
template <int KD, int ND, int NBG, int EPI>
__global__ __launch_bounds__(256) void moe_gemm(
    const uint16_t* __restrict__ Abase, const int* __restrict__ pair_tok,
    const uint16_t* __restrict__ Bw, const float* __restrict__ bias,
    uint16_t* __restrict__ Cout, const TileDesc* __restrict__ desc,
    const int* __restrict__ ntiles) {
  constexpr int NB = ND / 128;
  constexpr int SM = MAXT / 8;      // 9 mt-tiles per XCD

  // mapping: xcd = orig%8 (round-robin dispatch); within XCD: nb-group outer,
  // mt middle, nbr inner -> co-resident blocks share A panels + a small nb window.
  int orig = blockIdx.x;
  int xcd = orig & 7, local = orig >> 3;
  int nbq = local / (SM * NBG);
  int rem = local % (SM * NBG);
  int mt  = xcd * SM + rem / NBG;
  int nb  = nbq * NBG + rem % NBG;
  if (mt >= *ntiles) return;
  TileDesc d = desc[mt];

  __shared__ uint16_t As[128 * 32];
  __shared__ uint16_t Bs[128 * 32];
  __shared__ int rowA[128];

  int tid = threadIdx.x, lane = tid & 63, wave = tid >> 6;
  int wm = wave >> 1, wn = wave & 1;

  int idx0 = (wave * 2 + 0) * 64 + lane;
  int idx1 = (wave * 2 + 1) * 64 + lane;
  int ar0 = idx0 >> 2, kc0 = idx0 & 3;
  int ar1 = idx1 >> 2, kc1 = idx1 & 3;

  int ra0, ra1;
  if constexpr (EPI == 0) {
    if (tid < 128) rowA[tid] = (tid < d.rows) ? pair_tok[d.start + tid] : 0;
    __syncthreads();
    ra0 = rowA[ar0]; ra1 = rowA[ar1];
  } else {
    ra0 = d.start + ar0; ra1 = d.start + ar1;
  }

  const uint16_t* Bbase = Bw + ((size_t)d.e * ND + (size_t)nb * 128) * KD;

  f32x4 acc[4][4];
#pragma unroll
  for (int i = 0; i < 4; ++i)
#pragma unroll
    for (int j = 0; j < 4; ++j) acc[i][j] = (f32x4){0.f, 0.f, 0.f, 0.f};

  for (int kt = 0; kt < KD / 32; ++kt) {
    if (kt) __syncthreads();
    int kb = kt * 32;
    gload_lds16(Abase + (size_t)ra0 * KD + kb + kc0 * 8, &As[(wave * 2 + 0) * 512]);
    gload_lds16(Abase + (size_t)ra1 * KD + kb + kc1 * 8, &As[(wave * 2 + 1) * 512]);
    gload_lds16(Bbase + (size_t)ar0 * KD + kb + kc0 * 8, &Bs[(wave * 2 + 0) * 512]);
    gload_lds16(Bbase + (size_t)ar1 * KD + kb + kc1 * 8, &Bs[(wave * 2 + 1) * 512]);
    __syncthreads();

    short8x af[4], bfr[4];
#pragma unroll
    for (int i = 0; i < 4; ++i)
      af[i] = *(const short8x*)&As[(wm * 64 + i * 16 + (lane & 15)) * 32 + (lane >> 4) * 8];
#pragma unroll
    for (int j = 0; j < 4; ++j)
      bfr[j] = *(const short8x*)&Bs[(wn * 64 + j * 16 + (lane & 15)) * 32 + (lane >> 4) * 8];
#pragma unroll
    for (int i = 0; i < 4; ++i)
#pragma unroll
      for (int j = 0; j < 4; ++j)
        acc[i][j] = __builtin_amdgcn_mfma_f32_16x16x32_bf16(af[i], bfr[j], acc[i][j], 0, 0, 0);
  }

  // epilogue: C/D layout col=lane&15, row=(lane>>4)*4+q  [measured m89]
  int rq = (lane >> 4) * 4;
  int cl = lane & 15;
#pragma unroll
  for (int i = 0; i < 4; ++i) {
    int rb = wm * 64 + i * 16 + rq;
#pragma unroll
    for (int j = 0; j < 4; ++j) {
      int col = nb * 128 + wn * 64 + j * 16 + cl;
      float bv = bias[d.e * ND + col];
#pragma unroll
      for (int q = 0; q < 4; ++q) {
        int r = rb + q;
        if (r < d.rows) {
          float v = acc[i][j][q] + bv;
          if (EPI == 0) v = fmaxf(v, 0.f);
          Cout[(size_t)(d.start + r) * ND + col] = f2bf(v);
        }
      }
    }
  }
}

// ---------------- combine ----------------
__global__ __launch_bounds__(256) void combine_kernel(
    const uint16_t* __restrict__ po, const int* __restrict__ tok_pos,
    const float* __restrict__ topk_w, float* __restrict__ out) {
  int t = blockIdx.x;
  int c = threadIdx.x * 4;
  int p0 = tok_pos[t * 2], p1 = tok_pos[t * 2 + 1];
  float w0 = topk_w[t * 2], w1 = topk_w[t * 2 + 1];
  ushort4 a = *(const ushort4*)&po[(size_t)p0 * HD + c];
  ushort4 b = *(const ushort4*)&po[(size_t)p1 * HD + c];
  float4 o;
  o.x = w0 * bf2f(a.x) + w1 * bf2f(b.x);
  o.y = w0 * bf2f(a.y) + w1 * bf2f(b.y);
  o.z = w0 * bf2f(a.z) + w1 * bf2f(b.z);
  o.w = w0 * bf2f(a.w) + w1 * bf2f(b.w);
  *(float4*)&out[(size_t)t * HD + c] = o;
}

extern "C" void kernel_launch(void* const* d_in, const int* in_sizes, int n_in,
                              void* d_out, int out_size, void* d_ws, size_t ws_size,
                              hipStream_t stream) {
  const float* x      = (const float*)d_in[0];
  const float* gate_w = (const float*)d_in[1];
  const float* w1     = (const float*)d_in[2];
  const float* b1     = (const float*)d_in[3];
  const float* w2     = (const float*)d_in[4];
  const float* b2     = (const float*)d_in[5];
  float* out = (float*)d_out;
  (void)in_sizes; (void)n_in; (void)out_size; (void)ws_size;

  char* w = (char*)d_ws;
  size_t off = 0;
  auto alloc = [&](size_t bytes) -> void* {
    void* p = w + off;
    off = (off + bytes + 255) & ~(size_t)255;
    return p;
  };
  int*      meta     = (int*)alloc(256);
  int*      fill     = meta;
  int*      offsets  = (int*)alloc(256);
  int*      ntiles   = offsets + 8;
  TileDesc* desc     = (TileDesc*)alloc(sizeof(TileDesc) * 128);
  int*      topk_idx = (int*)alloc(sizeof(int) * P);
  float*    topk_w   = (float*)alloc(sizeof(float) * P);
  int*      tok_pos  = (int*)alloc(sizeof(int) * P);
  int*      pair_tok = (int*)alloc(sizeof(int) * PPAD);
  float*    psums    = (float*)alloc(sizeof(float) * RNB * NE);
  int*      pcounts  = (int*)alloc(sizeof(int) * RNB * NE);
  uint16_t* xb       = (uint16_t*)alloc((size_t)T * HD * 2);
  uint16_t* w1t      = (uint16_t*)alloc((size_t)NE * FD * HD * 2);
  uint16_t* w2t      = (uint16_t*)alloc((size_t)NE * HD * FD * 2);
  uint16_t* hidden   = (uint16_t*)alloc((size_t)PPAD * FD * 2);
  uint16_t* pout     = (uint16_t*)alloc((size_t)PPAD * HD * 2);

  hipMemsetAsync(meta, 0, 256, stream);
  cvt_x_kernel<<<(T * HD) / 1024, 256, 0, stream>>>(x, xb);
  transpose_cvt_kernel<<<dim3(FD / 64, HD / 64, NE), 256, 0, stream>>>(w1, w1t, HD, FD);
  transpose_cvt_kernel<<<dim3(HD / 64, FD / 64, NE), 256, 0, stream>>>(w2, w2t, FD, HD);
  router_kernel<<<RNB, 256, 0, stream>>>(x, gate_w, topk_idx, topk_w, psums, pcounts);
  finalize_kernel<<<1, 64, 0, stream>>>(pcounts, psums, offsets, desc, ntiles,
                                        out + (size_t)T * HD);
  scatter_kernel<<<T / 256, 256, 0, stream>>>(topk_idx, offsets, fill, pair_tok, tok_pos);
  // fc1: gather+relu; grid = NB(32) * MAXT(72) = 2304, co-resident ~8mt x 4nb per XCD
  moe_gemm<HD, FD, 4, 0><<<(FD / 128) * MAXT, 256, 0, stream>>>(
      xb, pair_tok, w1t, b1, hidden, desc, ntiles);
  // fc2: contiguous; grid = NB(8) * MAXT(72) = 576, co-resident ~4mt x 8nb per XCD
  moe_gemm<FD, HD, 8, 1><<<(HD / 128) * MAXT, 256, 0, stream>>>(
      hidden, pair_tok, w2t, b2, pout, desc, ntiles);
  combine_kernel<<<T, 256, 0, stream>>>(pout, tok_pos, topk_w, out);
}